// Round 3
// baseline (26834.698 us; speedup 1.0000x reference)
//
#include <hip/hip_runtime.h>

// SNLI attention-LSTM, MI355X. Round 3: R2's persistent design, workspace-fixed.
// R2 crashed from workspace overflow (~330 MB vs ~268 MB budget; R1's 258 MB
// passed). Changes vs R2:
//  - no pre-split emb table (-64 MB): scan gathers fp32 emb + splits on the
//    fly (R1-verified path) against resident weight registers.
//  - first/hsec stored as split bf16 hi/lo (-50 MB); GEMM writes split.
//  Total ~217 MB.
// Architecture: persistent lstm_scan (256 blocks, gate-per-wave resident
// weights, grid barrier/step), persistent attn_scan (128 blocks, 2 barriers/t),
// split-bf16 3-pass MFMA everywhere.

using u16 = unsigned short;
typedef short bf16x8 __attribute__((ext_vector_type(8)));
typedef float f32x4 __attribute__((ext_vector_type(4)));

constexpr int B  = 128;
constexpr int SP = 128;
constexpr int SH = 64;
constexpr int H  = 1024;
constexpr int E  = 300;
constexpr int NC = 4;
constexpr int G4H  = 4 * H;          // 4096
constexpr int EPAD = 320;            // E padded to multiple of 32
constexpr int KCAT = EPAD + H;       // 1344
constexpr int NB_L = 256;            // lstm persistent blocks (== CU count)
constexpr int NB_A = 128;            // attn persistent blocks

__device__ __forceinline__ float sigf(float x) { return 1.0f / (1.0f + __expf(-x)); }
__device__ __forceinline__ float tanh_fast(float x) {
    float e = __expf(2.0f * x);
    return 1.0f - 2.0f / (e + 1.0f);
}
__device__ __forceinline__ u16 f2bf(float x) {           // round-to-nearest-even
    union { float f; unsigned u; } v; v.f = x;
    unsigned r = v.u + 0x7fffu + ((v.u >> 16) & 1u);
    return (u16)(r >> 16);
}
__device__ __forceinline__ float bf2f(u16 h) {
    union { unsigned u; float f; } v; v.u = ((unsigned)h) << 16;
    return v.f;
}
__device__ __forceinline__ f32x4 mfma16(bf16x8 a, bf16x8 b, f32x4 c) {
    return __builtin_amdgcn_mfma_f32_16x16x32_bf16(a, b, c, 0, 0, 0);
}

// Grid barrier: monotonic counter (no reset races). Release fence before
// arrive; acquire fence after leaving the spin.
__device__ __forceinline__ void gbar(int* cnt, int target) {
    __syncthreads();
    __threadfence();
    if (threadIdx.x == 0) {
        atomicAdd(cnt, 1);
        while (atomicAdd(cnt, 0) < target) __builtin_amdgcn_s_sleep(4);
    }
    __syncthreads();
    __threadfence();
}

// ---------------------------------------------------------------------------
// Prep kernels
// ---------------------------------------------------------------------------
__global__ __launch_bounds__(256)
void wcat_split_kernel(const float* __restrict__ w_ih, const float* __restrict__ w_hh,
                       u16* __restrict__ dh, u16* __restrict__ dl)
{
    int col = blockIdx.x * 256 + threadIdx.x;
    int n = blockIdx.y;
    if (col >= KCAT) return;
    float v = 0.f;
    if (col < E)          v = w_ih[(size_t)n * E + col];
    else if (col >= EPAD) v = w_hh[(size_t)n * H + (col - EPAD)];
    u16 hi = f2bf(v);
    dh[(size_t)n * KCAT + col] = hi;
    dl[(size_t)n * KCAT + col] = f2bf(v - bf2f(hi));
}

// dst[n][k] = split(src[k][n]) for H x H weights (wy, wh).
__global__ __launch_bounds__(256)
void tsplit_kernel(const float* __restrict__ src, u16* __restrict__ dh, u16* __restrict__ dl)
{
    int k = blockIdx.x * 256 + threadIdx.x;
    int n = blockIdx.y;
    float v = src[(size_t)k * H + n];
    u16 hi = f2bf(v);
    dh[(size_t)n * H + k] = hi;
    dl[(size_t)n * H + k] = f2bf(v - bf2f(hi));
}

// [wr | wt] transposed-split: dst[n][k], n<H -> wr[k][n], else wt[k][n-H].
__global__ __launch_bounds__(256)
void wrt_split_kernel(const float* __restrict__ wr, const float* __restrict__ wt,
                      u16* __restrict__ dh, u16* __restrict__ dl)
{
    int k = blockIdx.x * 256 + threadIdx.x;    // 0..H-1
    int n = blockIdx.y;                        // 0..2047
    float v = (n < H) ? wr[(size_t)k * H + n] : wt[(size_t)k * H + (n - H)];
    u16 hi = f2bf(v);
    dh[(size_t)n * H + k] = hi;
    dl[(size_t)n * H + k] = f2bf(v - bf2f(hi));
}

// ---------------------------------------------------------------------------
// Persistent LSTM scan. 256 blocks x 256 thr. Block: bx = k-tile (16 units),
// by = m-quarter (32 rows). Wave g owns gate g: weights in 336 VGPRs.
// ---------------------------------------------------------------------------
template<int PREMISE>
__global__ __launch_bounds__(256, 1)
void lstm_scan(const int* __restrict__ toks, int S,
               const float* __restrict__ emb,
               const u16* __restrict__ Wh, const u16* __restrict__ Wl,
               const float* __restrict__ b_ih, const float* __restrict__ b_hh,
               u16* __restrict__ h0h, u16* __restrict__ h0l,
               u16* __restrict__ h1h, u16* __restrict__ h1l,
               float* __restrict__ c, float* __restrict__ hmask,
               float* __restrict__ cmask,
               u16* __restrict__ seq_hi, u16* __restrict__ seq_lo,
               int* __restrict__ bar)
{
    const int tid  = threadIdx.x;
    const int lane = tid & 63;
    const int g    = tid >> 6;           // gate = wave
    const int l15  = lane & 15;
    const int lk8  = (lane >> 4) * 8;
    const int bx   = blockIdx.x & 63;
    const int by   = blockIdx.x >> 6;    // 0..3
    const int k0   = bx * 16;
    const int m0   = by * 32;

    // ---- resident weights: rows n = g*H + k0 + l15, cols ks*32 + lk8 ----
    bf16x8 wh_r[42], wl_r[42];
    {
        const u16* ph = Wh + (size_t)(g * H + k0 + l15) * KCAT + lk8;
        const u16* pl = Wl + (size_t)(g * H + k0 + l15) * KCAT + lk8;
#pragma unroll
        for (int ks = 0; ks < 42; ++ks) {
            wh_r[ks] = *(const bf16x8*)(ph + ks * 32);
            wl_r[ks] = *(const bf16x8*)(pl + ks * 32);
        }
    }
    const int ke = k0 + (tid & 15);
    const float bs0 = b_ih[0 * H + ke] + b_hh[0 * H + ke];
    const float bs1 = b_ih[1 * H + ke] + b_hh[1 * H + ke];
    const float bs2 = b_ih[2 * H + ke] + b_hh[2 * H + ke];
    const float bs3 = b_ih[3 * H + ke] + b_hh[3 * H + ke];

    __shared__ float gt[4][32][17];

    for (int t = 0; t < S; ++t) {
        const u16* hinh = (t & 1) ? h1h : h0h;
        const u16* hinl = (t & 1) ? h1l : h0l;
        u16* houth = (t & 1) ? h0h : h1h;
        u16* houtl = (t & 1) ? h0l : h1l;

        const float* ea[2];
#pragma unroll
        for (int mt = 0; mt < 2; ++mt) {
            int row = m0 + mt * 16 + l15;
            int tok = toks[row * S + t];
            ea[mt] = emb + (size_t)tok * E + lk8;
        }
        const u16* ah = hinh + (size_t)(m0 + l15) * H + lk8;
        const ptrdiff_t dH = hinl - hinh;

        f32x4 acc[2] = {{0.f,0.f,0.f,0.f},{0.f,0.f,0.f,0.f}};

        // emb segment ks 0..8: cols ks*32+lk8 .. +7, all < 288+24+8 <= 300? max 287+8?
        // max col = 8*32 + 24 + 7 = 287 < 300 -> unguarded float4 loads.
#pragma unroll
        for (int ks = 0; ks < 9; ++ks) {
#pragma unroll
            for (int mt = 0; mt < 2; ++mt) {
                float4 f0 = *(const float4*)(ea[mt] + ks * 32);
                float4 f1 = *(const float4*)(ea[mt] + ks * 32 + 4);
                float v[8] = {f0.x, f0.y, f0.z, f0.w, f1.x, f1.y, f1.z, f1.w};
                bf16x8 a_hi, a_lo;
#pragma unroll
                for (int j = 0; j < 8; ++j) {
                    u16 hi = f2bf(v[j]);
                    a_hi[j] = (short)hi;
                    a_lo[j] = (short)f2bf(v[j] - bf2f(hi));
                }
                acc[mt] = mfma16(a_hi, wh_r[ks], acc[mt]);
                acc[mt] = mfma16(a_lo, wh_r[ks], acc[mt]);
                acc[mt] = mfma16(a_hi, wl_r[ks], acc[mt]);
            }
        }
        {   // ks = 9: cols 288 + lk8 + j, guard k < E (weight pad cols are 0)
#pragma unroll
            for (int mt = 0; mt < 2; ++mt) {
                float v[8];
#pragma unroll
                for (int j = 0; j < 8; ++j) {
                    int k = 288 + lk8 + j;
                    v[j] = (k < E) ? ea[mt][k - lk8] : 0.f;
                }
                bf16x8 a_hi, a_lo;
#pragma unroll
                for (int j = 0; j < 8; ++j) {
                    u16 hi = f2bf(v[j]);
                    a_hi[j] = (short)hi;
                    a_lo[j] = (short)f2bf(v[j] - bf2f(hi));
                }
                acc[mt] = mfma16(a_hi, wh_r[9], acc[mt]);
                acc[mt] = mfma16(a_lo, wh_r[9], acc[mt]);
                acc[mt] = mfma16(a_hi, wl_r[9], acc[mt]);
            }
        }
        // h segment: ks 0..31 (weight cols 320..1343)
#pragma unroll
        for (int ks = 0; ks < 32; ++ks) {
#pragma unroll
            for (int mt = 0; mt < 2; ++mt) {
                const u16* p = ah + mt * 16 * H + ks * 32;
                bf16x8 a_hi = *(const bf16x8*)(p);
                bf16x8 a_lo = *(const bf16x8*)(p + dH);
                acc[mt] = mfma16(a_hi, wh_r[10 + ks], acc[mt]);
                acc[mt] = mfma16(a_lo, wh_r[10 + ks], acc[mt]);
                acc[mt] = mfma16(a_hi, wl_r[10 + ks], acc[mt]);
            }
        }

        // ---- gate exchange via LDS ----
#pragma unroll
        for (int mt = 0; mt < 2; ++mt)
#pragma unroll
            for (int j = 0; j < 4; ++j)
                gt[g][mt * 16 + (lane >> 4) * 4 + j][l15] = acc[mt][j];
        __syncthreads();

        // ---- cell epilogue: 2 (m, ke) elements per thread ----
#pragma unroll
        for (int i = 0; i < 2; ++i) {
            int ml = (tid >> 4) + i * 16;        // 0..31
            int m  = m0 + ml;
            size_t idx = (size_t)m * H + ke;
            float gi = gt[0][ml][tid & 15] + bs0;
            float gf = gt[1][ml][tid & 15] + bs1;
            float gg = gt[2][ml][tid & 15] + bs2;
            float go = gt[3][ml][tid & 15] + bs3;
            float c2 = sigf(gf) * c[idx] + sigf(gi) * tanh_fast(gg);
            float h2 = sigf(go) * tanh_fast(c2);
            c[idx] = c2;
            u16 hh = f2bf(h2);
            houth[idx] = hh;
            houtl[idx] = f2bf(h2 - bf2f(hh));
            float mk = (toks[m * S + t] != 0) ? 1.f : 0.f;
            float hmv = mk * h2 + (1.f - mk) * hmask[idx];
            hmask[idx] = hmv;
            u16 mh = f2bf(hmv);
            u16 mlv = f2bf(hmv - bf2f(mh));
            if (PREMISE) {
                float cmv = mk * c2 + (1.f - mk) * cmask[idx];
                cmask[idx] = cmv;
                size_t yi = ((size_t)m * SP + t) * H + ke;   // Y [B][SP][H]
                seq_hi[yi] = mh; seq_lo[yi] = mlv;
            } else {
                size_t oi = ((size_t)t * B + m) * H + ke;    // outh [SH][B][H]
                seq_hi[oi] = mh; seq_lo[oi] = mlv;
            }
        }
        if (t + 1 < S) gbar(bar, (t + 1) * NB_L);
        else __syncthreads();
    }
}

// ---------------------------------------------------------------------------
// Persistent attention scan. 128 blocks x 256 thr; block = batch row b.
// Per t: phase A srt = r_s @ WrtT (grid-wide wave tiling), barrier,
// phase B scores (s in LDS) + phase C softmax + r update, barrier.
// first/hsec are split bf16 hi/lo.
// ---------------------------------------------------------------------------
__global__ __launch_bounds__(256, 1)
void attn_scan(const u16* __restrict__ firstH, const u16* __restrict__ firstL, // [B*SP][H]
               const u16* __restrict__ hsecH, const u16* __restrict__ hsecL,   // [SH*B][H]
               const u16* __restrict__ Wrth, const u16* __restrict__ Wrtl,     // [2048][1024]
               const u16* __restrict__ Yh, const u16* __restrict__ Yl,         // [B*SP][H]
               const float* __restrict__ wv,      // [H]
               const int* __restrict__ ptoks, const int* __restrict__ htoks,
               float* __restrict__ srt,           // [B][2048] (secr | rwt)
               u16* __restrict__ rh, u16* __restrict__ rl,  // [B][H] split r
               float* __restrict__ r,             // [B][H] fp32
               int* __restrict__ bar)
{
    const int tid  = threadIdx.x;
    const int lane = tid & 63;
    const int w    = tid >> 6;
    const int l15  = lane & 15;
    const int lk8  = (lane >> 4) * 8;
    const int b    = blockIdx.x;

    __shared__ float sArr[SP];
    __shared__ float al[SP];
    __shared__ float red[SP];

    // hoisted: per-lane wv slice for score dot
    float wv_e[16];
#pragma unroll
    for (int e = 0; e < 16; ++e) wv_e[e] = wv[lane + e * 64];

    // phase-A tile assignment: 512 waves x 2 n-tiles = 128 n-tiles x 8 m-tiles
    const int gw  = blockIdx.x * 4 + w;
    const int n0  = (gw & 63) * 32;          // two adjacent 16-col tiles
    const int pm0 = (gw >> 6) * 16;          // 16 batch rows
    const ptrdiff_t dA = rl - rh;
    const ptrdiff_t dB = Wrtl - Wrth;

    int tgt = 0;
    for (int t = 0; t < SH; ++t) {
        // ---- phase A: srt[m][n] for n in {n0, n0+16} ----
        {
            const u16* ap  = rh + (size_t)(pm0 + l15) * H + lk8;
            const u16* bp0 = Wrth + (size_t)(n0 + l15) * H + lk8;
            const u16* bp1 = Wrth + (size_t)(n0 + 16 + l15) * H + lk8;
            f32x4 a0 = {0.f,0.f,0.f,0.f}, a1 = {0.f,0.f,0.f,0.f};
#pragma unroll 4
            for (int ks = 0; ks < 32; ++ks) {
                bf16x8 ahi = *(const bf16x8*)(ap + ks * 32);
                bf16x8 alo = *(const bf16x8*)(ap + dA + ks * 32);
                bf16x8 b0h = *(const bf16x8*)(bp0 + ks * 32);
                bf16x8 b0l = *(const bf16x8*)(bp0 + dB + ks * 32);
                a0 = mfma16(ahi, b0h, a0);
                a0 = mfma16(alo, b0h, a0);
                a0 = mfma16(ahi, b0l, a0);
                bf16x8 b1h = *(const bf16x8*)(bp1 + ks * 32);
                bf16x8 b1l = *(const bf16x8*)(bp1 + dB + ks * 32);
                a1 = mfma16(ahi, b1h, a1);
                a1 = mfma16(alo, b1h, a1);
                a1 = mfma16(ahi, b1l, a1);
            }
#pragma unroll
            for (int j = 0; j < 4; ++j) {
                int mrow = pm0 + (lane >> 4) * 4 + j;
                srt[(size_t)mrow * 2048 + n0 + l15]      = a0[j];
                srt[(size_t)mrow * 2048 + n0 + 16 + l15] = a1[j];
            }
        }
        tgt += NB_A;
        gbar(bar, tgt);

        // ---- phase B: scores for this block's b; s stays in LDS ----
        {
            float hsum[16];
            const u16* hbh = hsecH + ((size_t)t * B + b) * H;
            const u16* hbl = hsecL + ((size_t)t * B + b) * H;
            const float* sb = srt + (size_t)b * 2048;
#pragma unroll
            for (int e = 0; e < 16; ++e) {
                int hh = lane + e * 64;
                hsum[e] = bf2f(hbh[hh]) + bf2f(hbl[hh]) + sb[hh];
            }
            for (int pp = 0; pp < 32; ++pp) {
                int p = w * 32 + pp;
                const u16* fph = firstH + ((size_t)b * SP + p) * H;
                const u16* fpl = firstL + ((size_t)b * SP + p) * H;
                float acc = 0.f;
#pragma unroll
                for (int e = 0; e < 16; ++e) {
                    int hh = lane + e * 64;
                    acc += tanh_fast(bf2f(fph[hh]) + bf2f(fpl[hh]) + hsum[e]) * wv_e[e];
                }
#pragma unroll
                for (int off = 32; off; off >>= 1) acc += __shfl_xor(acc, off);
                if (lane == 0)
                    sArr[p] = acc + ((ptoks[b * SP + p] != 0) ? 0.f : -1000.f);
            }
        }
        __syncthreads();

        // ---- phase C: softmax + r_t = alpha@Y + tanh(rwt); masked carry ----
        {
            if (tid < SP) { float v = sArr[tid]; al[tid] = v; red[tid] = v; }
            __syncthreads();
            for (int off = 64; off; off >>= 1) {
                if (tid < off) red[tid] = fmaxf(red[tid], red[tid + off]);
                __syncthreads();
            }
            float mx = red[0];
            __syncthreads();
            if (tid < SP) { float e = __expf(al[tid] - mx); al[tid] = e; red[tid] = e; }
            __syncthreads();
            for (int off = 64; off; off >>= 1) {
                if (tid < off) red[tid] += red[tid + off];
                __syncthreads();
            }
            float inv = 1.f / red[0];
            __syncthreads();
            if (tid < SP) al[tid] *= inv;
            __syncthreads();

            const int h0 = tid * 4;
            float a0 = 0.f, a1 = 0.f, a2 = 0.f, a3 = 0.f;
            const u16* yhp = Yh + (size_t)b * SP * H + h0;
            const u16* ylp = Yl + (size_t)b * SP * H + h0;
#pragma unroll 2
            for (int p = 0; p < SP; ++p) {
                float a = al[p];
                uint2 vh = *(const uint2*)(yhp + (size_t)p * H);
                uint2 vl = *(const uint2*)(ylp + (size_t)p * H);
                a0 += a * (__uint_as_float(vh.x << 16) + __uint_as_float(vl.x << 16));
                a1 += a * (__uint_as_float(vh.x & 0xffff0000u) + __uint_as_float(vl.x & 0xffff0000u));
                a2 += a * (__uint_as_float(vh.y << 16) + __uint_as_float(vl.y << 16));
                a3 += a * (__uint_as_float(vh.y & 0xffff0000u) + __uint_as_float(vl.y & 0xffff0000u));
            }
            float mk = (htoks[b * SH + t] != 0) ? 1.f : 0.f;
            const float* rwt = srt + (size_t)b * 2048 + H;
            float4 ro = *(const float4*)(r + (size_t)b * H + h0);
            float rn0 = a0 + tanh_fast(rwt[h0 + 0]);
            float rn1 = a1 + tanh_fast(rwt[h0 + 1]);
            float rn2 = a2 + tanh_fast(rwt[h0 + 2]);
            float rn3 = a3 + tanh_fast(rwt[h0 + 3]);
            float4 rv;
            rv.x = mk * rn0 + (1.f - mk) * ro.x;
            rv.y = mk * rn1 + (1.f - mk) * ro.y;
            rv.z = mk * rn2 + (1.f - mk) * ro.z;
            rv.w = mk * rn3 + (1.f - mk) * ro.w;
            *(float4*)(r + (size_t)b * H + h0) = rv;
            u16 q0 = f2bf(rv.x), q1 = f2bf(rv.y), q2 = f2bf(rv.z), q3 = f2bf(rv.w);
            ushort4 sh = make_ushort4(q0, q1, q2, q3);
            ushort4 sl = make_ushort4(f2bf(rv.x - bf2f(q0)), f2bf(rv.y - bf2f(q1)),
                                      f2bf(rv.z - bf2f(q2)), f2bf(rv.w - bf2f(q3)));
            *(ushort4*)(rh + (size_t)b * H + h0) = sh;
            *(ushort4*)(rl + (size_t)b * H + h0) = sl;
        }
        if (t + 1 < SH) { tgt += NB_A; gbar(bar, tgt); }
    }
}

// ---------------------------------------------------------------------------
// Split-bf16 MFMA GEMM: C = A[M,K] @ B^T, B stored [N][K] hi/lo.
// SPLITOUT: write C as split bf16 hi/lo (u16) instead of fp32.
// ---------------------------------------------------------------------------
template<bool SPLITOUT>
__global__ __launch_bounds__(256)
void gemm_mfma_kernel(const u16* __restrict__ Ah, const u16* __restrict__ Al,
                      const u16* __restrict__ Bh, const u16* __restrict__ Bl,
                      float* __restrict__ C, u16* __restrict__ Ch, u16* __restrict__ Cl,
                      int M, int N, int K)
{
    const int tid  = threadIdx.x;
    const int lane = tid & 63;
    const int wave = tid >> 6;
    const int l15  = lane & 15;
    const int lk8  = (lane >> 4) * 8;
    const int m0   = blockIdx.y * 64 + wave * 16;
    const int n0   = blockIdx.x * 64;

    const u16* ahp = Ah + (size_t)(m0 + l15) * K + lk8;
    const u16* alp = Al + (size_t)(m0 + l15) * K + lk8;
    const u16* bhp[4]; const u16* blp[4];
#pragma unroll
    for (int nt = 0; nt < 4; ++nt) {
        size_t o = (size_t)(n0 + nt * 16 + l15) * K + lk8;
        bhp[nt] = Bh + o; blp[nt] = Bl + o;
    }
    f32x4 acc[4] = {{0.f,0.f,0.f,0.f},{0.f,0.f,0.f,0.f},
                    {0.f,0.f,0.f,0.f},{0.f,0.f,0.f,0.f}};
    const int nks = K >> 5;
#pragma unroll 2
    for (int ks = 0; ks < nks; ++ks) {
        bf16x8 a_hi = *(const bf16x8*)(ahp + ks * 32);
        bf16x8 a_lo = *(const bf16x8*)(alp + ks * 32);
#pragma unroll
        for (int nt = 0; nt < 4; ++nt) {
            bf16x8 b_hi = *(const bf16x8*)(bhp[nt] + ks * 32);
            bf16x8 b_lo = *(const bf16x8*)(blp[nt] + ks * 32);
            acc[nt] = mfma16(a_hi, b_hi, acc[nt]);
            acc[nt] = mfma16(a_lo, b_hi, acc[nt]);
            acc[nt] = mfma16(a_hi, b_lo, acc[nt]);
        }
    }
#pragma unroll
    for (int nt = 0; nt < 4; ++nt)
#pragma unroll
        for (int j = 0; j < 4; ++j) {
            int m = m0 + (lane >> 4) * 4 + j;
            size_t idx = (size_t)m * N + n0 + nt * 16 + l15;
            if (SPLITOUT) {
                float v = acc[nt][j];
                u16 hi = f2bf(v);
                Ch[idx] = hi;
                Cl[idx] = f2bf(v - bf2f(hi));
            } else {
                C[idx] = acc[nt][j];
            }
        }
}

// ---------------------------------------------------------------------------
// Skinny fp32 GEMM (M=128): tile 32x64, BK=16, 256 thr, dbuf (verified).
// ---------------------------------------------------------------------------
template<bool ACC>
__global__ __launch_bounds__(256)
void skinny_kernel(const float* __restrict__ A,
                   const float* __restrict__ B1, float* __restrict__ C1,
                   const float* __restrict__ B2, float* __restrict__ C2,
                   int K, int N, int ntiles)
{
    const int tid = threadIdx.x;
    const int tx = tid & 15, ty = tid >> 4;
    const int bx = blockIdx.x;
    const float* Bw = (bx < ntiles) ? B1 : B2;
    float* C       = (bx < ntiles) ? C1 : C2;
    const int n0 = ((bx < ntiles) ? bx : bx - ntiles) * 64;
    const int m0 = blockIdx.y * 32;

    __shared__ float As[2][16][34];
    __shared__ float Bs[2][16][68];
    const int sq = tid & 15, sm = tid >> 4;
    const int nb = tid & 63, kb = tid >> 6;

    float ra[2], rb[4];
    auto ldA = [&](int k0, int rr) -> float {
        return A[(size_t)(m0 + sm + 16 * rr) * K + k0 + sq];
    };
    auto ldB = [&](int k0, int rr) -> float {
        return Bw[(size_t)(k0 + kb + 4 * rr) * N + n0 + nb];
    };

    float acc[2][4] = {};
    ra[0] = ldA(0, 0); ra[1] = ldA(0, 1);
#pragma unroll
    for (int rr = 0; rr < 4; ++rr) rb[rr] = ldB(0, rr);
    As[0][sq][sm] = ra[0]; As[0][sq][sm + 16] = ra[1];
#pragma unroll
    for (int rr = 0; rr < 4; ++rr) Bs[0][kb + 4 * rr][nb] = rb[rr];
    __syncthreads();

    const int NKT = K / 16;
    for (int kt = 0; kt < NKT; ++kt) {
        const int buf = kt & 1;
        if (kt + 1 < NKT) {
            int k0 = (kt + 1) * 16;
            ra[0] = ldA(k0, 0); ra[1] = ldA(k0, 1);
#pragma unroll
            for (int rr = 0; rr < 4; ++rr) rb[rr] = ldB(k0, rr);
        }
#pragma unroll
        for (int qq = 0; qq < 16; ++qq) {
            float2 a2 = *(const float2*)&As[buf][qq][ty * 2];
            float4 b4 = *(const float4*)&Bs[buf][qq][tx * 4];
            acc[0][0] += a2.x * b4.x; acc[0][1] += a2.x * b4.y;
            acc[0][2] += a2.x * b4.z; acc[0][3] += a2.x * b4.w;
            acc[1][0] += a2.y * b4.x; acc[1][1] += a2.y * b4.y;
            acc[1][2] += a2.y * b4.z; acc[1][3] += a2.y * b4.w;
        }
        if (kt + 1 < NKT) {
            const int nbuf = buf ^ 1;
            As[nbuf][sq][sm] = ra[0]; As[nbuf][sq][sm + 16] = ra[1];
#pragma unroll
            for (int rr = 0; rr < 4; ++rr) Bs[nbuf][kb + 4 * rr][nb] = rb[rr];
            __syncthreads();
        }
    }
#pragma unroll
    for (int i = 0; i < 2; ++i) {
        int m = m0 + ty * 2 + i;
        float* cp = &C[(size_t)m * N + n0 + tx * 4];
        float4 v = make_float4(acc[i][0], acc[i][1], acc[i][2], acc[i][3]);
        if (ACC) {
            float4 o = *(const float4*)cp;
            v.x += o.x; v.y += o.y; v.z += o.z; v.w += o.w;
        }
        *(float4*)cp = v;
    }
}

// logits -> softmax over 4 classes
__global__ __launch_bounds__(256)
void final_kernel(const float* __restrict__ pre,
                  const float* __restrict__ fc_w,
                  const float* __restrict__ fc_b,
                  float* __restrict__ out)
{
    int b = blockIdx.x;
    float acc[NC] = {0.f, 0.f, 0.f, 0.f};
    for (int k = threadIdx.x; k < H; k += 256) {
        float hs = tanh_fast(pre[(size_t)b * H + k]);
#pragma unroll
        for (int cc = 0; cc < NC; ++cc) acc[cc] += hs * fc_w[cc * H + k];
    }
    __shared__ float red[NC][256];
#pragma unroll
    for (int cc = 0; cc < NC; ++cc) red[cc][threadIdx.x] = acc[cc];
    __syncthreads();
    for (int off = 128; off > 0; off >>= 1) {
        if (threadIdx.x < off)
#pragma unroll
            for (int cc = 0; cc < NC; ++cc)
                red[cc][threadIdx.x] += red[cc][threadIdx.x + off];
        __syncthreads();
    }
    if (threadIdx.x == 0) {
        float l[NC], mx = -1e30f;
#pragma unroll
        for (int cc = 0; cc < NC; ++cc) { l[cc] = red[cc][0] + fc_b[cc]; mx = fmaxf(mx, l[cc]); }
        float sum = 0.f;
#pragma unroll
        for (int cc = 0; cc < NC; ++cc) { l[cc] = __expf(l[cc] - mx); sum += l[cc]; }
#pragma unroll
        for (int cc = 0; cc < NC; ++cc) out[b * NC + cc] = l[cc] / sum;
    }
}

extern "C" void kernel_launch(void* const* d_in, const int* in_sizes, int n_in,
                              void* d_out, int out_size, void* d_ws, size_t ws_size,
                              hipStream_t stream)
{
    const int*   prem   = (const int*)d_in[0];
    const int*   hyp    = (const int*)d_in[1];
    const float* emb    = (const float*)d_in[2];
    const float* w_ih_p = (const float*)d_in[3];
    const float* w_hh_p = (const float*)d_in[4];
    const float* b_ih_p = (const float*)d_in[5];
    const float* b_hh_p = (const float*)d_in[6];
    const float* w_ih_h = (const float*)d_in[7];
    const float* w_hh_h = (const float*)d_in[8];
    const float* b_ih_h = (const float*)d_in[9];
    const float* b_hh_h = (const float*)d_in[10];
    const float* wy     = (const float*)d_in[11];
    const float* wh     = (const float*)d_in[12];
    const float* wr     = (const float*)d_in[13];
    const float* wv     = (const float*)d_in[14];
    const float* wt     = (const float*)d_in[15];
    const float* wp     = (const float*)d_in[16];
    const float* wx     = (const float*)d_in[17];
    const float* fc_w   = (const float*)d_in[18];
    const float* fc_b   = (const float*)d_in[19];
    float* out = (float*)d_out;
    (void)in_sizes; (void)n_in; (void)out_size; (void)ws_size;

    char* wsc = (char*)d_ws;
    size_t off = 0;
    auto alloc = [&](size_t bytes) -> void* {
        void* p = wsc + off;
        off += (bytes + 255) & ~(size_t)255;
        return p;
    };
    // split weight packs (~44 MB)
    u16* Wp_hi  = (u16*)alloc((size_t)G4H * KCAT * 2);
    u16* Wp_lo  = (u16*)alloc((size_t)G4H * KCAT * 2);
    u16* Wq_hi  = (u16*)alloc((size_t)G4H * KCAT * 2);
    u16* Wq_lo  = (u16*)alloc((size_t)G4H * KCAT * 2);
    u16* wyT_hi = (u16*)alloc((size_t)H * H * 2);
    u16* wyT_lo = (u16*)alloc((size_t)H * H * 2);
    u16* whT_hi = (u16*)alloc((size_t)H * H * 2);
    u16* whT_lo = (u16*)alloc((size_t)H * H * 2);
    u16* WrtH   = (u16*)alloc((size_t)2 * H * H * 2);
    u16* WrtL   = (u16*)alloc((size_t)2 * H * H * 2);
    // sequence outputs + hoisted GEMM outputs, all split bf16 (~151 MB)
    u16* Y_hi   = (u16*)alloc((size_t)B * SP * H * 2);
    u16* Y_lo   = (u16*)alloc((size_t)B * SP * H * 2);
    u16* OH_hi  = (u16*)alloc((size_t)SH * B * H * 2);
    u16* OH_lo  = (u16*)alloc((size_t)SH * B * H * 2);
    u16* firstH = (u16*)alloc((size_t)B * SP * H * 2);
    u16* firstL = (u16*)alloc((size_t)B * SP * H * 2);
    u16* hsecH  = (u16*)alloc((size_t)SH * B * H * 2);
    u16* hsecL  = (u16*)alloc((size_t)SH * B * H * 2);
    // h ping-pong (split) — contiguous for one memset
    const size_t BH = (size_t)B * H;
    u16* h0h = (u16*)alloc(BH * 2);
    u16* h0l = (u16*)alloc(BH * 2);
    u16* h1h = (u16*)alloc(BH * 2);
    u16* h1l = (u16*)alloc(BH * 2);
    // c, hm, cm contiguous for one memset
    float* cbuf = (float*)alloc(BH * 4);
    float* hm   = (float*)alloc(BH * 4);
    float* cm   = (float*)alloc(BH * 4);
    float* r    = (float*)alloc(BH * 4);
    u16*   rh   = (u16*)alloc(BH * 2);
    u16*   rl   = (u16*)alloc(BH * 2);
    float* srt  = (float*)alloc((size_t)B * 2048 * 4);
    float* pre  = (float*)alloc(BH * 4);
    int*   bars = (int*)alloc(256);
    int* barP = bars + 0; int* barH = bars + 1; int* barA = bars + 2;

    // -------- one-time splits --------
    dim3 gW((KCAT + 255) / 256, G4H);
    wcat_split_kernel<<<gW, 256, 0, stream>>>(w_ih_p, w_hh_p, Wp_hi, Wp_lo);
    wcat_split_kernel<<<gW, 256, 0, stream>>>(w_ih_h, w_hh_h, Wq_hi, Wq_lo);
    tsplit_kernel<<<dim3(H / 256, H), 256, 0, stream>>>(wy, wyT_hi, wyT_lo);
    tsplit_kernel<<<dim3(H / 256, H), 256, 0, stream>>>(wh, whT_hi, whT_lo);
    wrt_split_kernel<<<dim3(H / 256, 2 * H), 256, 0, stream>>>(wr, wt, WrtH, WrtL);

    hipMemsetAsync(h0h, 0, 4 * BH * 2, stream);   // h0h,h0l,h1h,h1l
    hipMemsetAsync(cbuf, 0, 3 * BH * 4, stream);  // c, hm, cm
    hipMemsetAsync(r, 0, BH * 4, stream);
    hipMemsetAsync(rh, 0, 2 * BH * 2, stream);    // rh, rl
    hipMemsetAsync(bars, 0, 256, stream);

    // -------- premise LSTM (persistent) --------
    lstm_scan<1><<<NB_L, 256, 0, stream>>>(
        prem, SP, emb, Wp_hi, Wp_lo, b_ih_p, b_hh_p,
        h0h, h0l, h1h, h1l, cbuf, hm, cm, Y_hi, Y_lo, barP);

    // -------- hypothesis LSTM: h=0, c = cm --------
    hipMemsetAsync(h0h, 0, 4 * BH * 2, stream);
    hipMemsetAsync(hm, 0, BH * 4, stream);
    lstm_scan<0><<<NB_L, 256, 0, stream>>>(
        hyp, SH, emb, Wq_hi, Wq_lo, b_ih_h, b_hh_h,
        h0h, h0l, h1h, h1l, cm, hm, (float*)nullptr, OH_hi, OH_lo, barH);
    // hm = out_h_last

    // -------- hoisted GEMMs (split-in, split-out) --------
    gemm_mfma_kernel<true><<<dim3(H / 64, (B * SP) / 64), 256, 0, stream>>>(
        Y_hi, Y_lo, wyT_hi, wyT_lo, nullptr, firstH, firstL, B * SP, H, H);
    gemm_mfma_kernel<true><<<dim3(H / 64, (SH * B) / 64), 256, 0, stream>>>(
        OH_hi, OH_lo, whT_hi, whT_lo, nullptr, hsecH, hsecL, SH * B, H, H);

    // -------- attention scan (persistent) --------
    attn_scan<<<NB_A, 256, 0, stream>>>(
        firstH, firstL, hsecH, hsecL, WrtH, WrtL, Y_hi, Y_lo, wv, prem, hyp,
        srt, rh, rl, r, barA);

    // -------- final projection + softmax --------
    skinny_kernel<false><<<dim3(16, 4), 256, 0, stream>>>(r,  wp, pre, nullptr, nullptr, H, H, 16);
    skinny_kernel<true ><<<dim3(16, 4), 256, 0, stream>>>(hm, wx, pre, nullptr, nullptr, H, H, 16);
    final_kernel<<<B, 256, 0, stream>>>(pre, fc_w, fc_b, out);
}

// Round 4
// 24299.484 us; speedup vs baseline: 1.1043x; 1.1043x over previous
//
#include <hip/hip_runtime.h>

// SNLI attention-LSTM, MI355X. Round 4: fix the grid-barrier convoy.
// R3 counters: lstm_scan 11.15 ms with MfmaUtil 1.9% / VALUBusy 3.5% / HBM 1%
// -> all idle -> barrier-bound. Cause: spin via atomicAdd(cnt,0) = device RMW
// on one cacheline from 256 spinners (RMWs serialize; arrivals starve).
// Changes vs R3 (no numeric changes):
//  - poll with relaxed atomic LOADs (agent scope); arrival = one fetch_add.
//  - release fence before __syncthreads on arrive (all waves flushed before
//    the counter bump); acquire fence after wait.
//  - lstm_scan: emb-segment MFMAs (h-independent) issued BEFORE the wait.

using u16 = unsigned short;
typedef short bf16x8 __attribute__((ext_vector_type(8)));
typedef float f32x4 __attribute__((ext_vector_type(4)));

constexpr int B  = 128;
constexpr int SP = 128;
constexpr int SH = 64;
constexpr int H  = 1024;
constexpr int E  = 300;
constexpr int NC = 4;
constexpr int G4H  = 4 * H;          // 4096
constexpr int EPAD = 320;            // E padded to multiple of 32
constexpr int KCAT = EPAD + H;       // 1344
constexpr int NB_L = 256;            // lstm persistent blocks (== CU count)
constexpr int NB_A = 128;            // attn persistent blocks

__device__ __forceinline__ float sigf(float x) { return 1.0f / (1.0f + __expf(-x)); }
__device__ __forceinline__ float tanh_fast(float x) {
    float e = __expf(2.0f * x);
    return 1.0f - 2.0f / (e + 1.0f);
}
__device__ __forceinline__ u16 f2bf(float x) {           // round-to-nearest-even
    union { float f; unsigned u; } v; v.f = x;
    unsigned r = v.u + 0x7fffu + ((v.u >> 16) & 1u);
    return (u16)(r >> 16);
}
__device__ __forceinline__ float bf2f(u16 h) {
    union { unsigned u; float f; } v; v.u = ((unsigned)h) << 16;
    return v.f;
}
__device__ __forceinline__ f32x4 mfma16(bf16x8 a, bf16x8 b, f32x4 c) {
    return __builtin_amdgcn_mfma_f32_16x16x32_bf16(a, b, c, 0, 0, 0);
}

// ---- grid barrier: RMW only on arrival; poll with relaxed atomic loads ----
__device__ __forceinline__ void gbar_arrive(int* cnt) {
    __threadfence();                 // each wave flushes its stores
    __syncthreads();                 // ... all waves done flushing
    if (threadIdx.x == 0)
        __hip_atomic_fetch_add(cnt, 1, __ATOMIC_RELAXED, __HIP_MEMORY_SCOPE_AGENT);
}
__device__ __forceinline__ void gbar_wait(int* cnt, int target) {
    if (threadIdx.x == 0) {
        while (__hip_atomic_load(cnt, __ATOMIC_RELAXED, __HIP_MEMORY_SCOPE_AGENT) < target)
            __builtin_amdgcn_s_sleep(1);
    }
    __syncthreads();
    __threadfence();                 // acquire: invalidate caches
}

// ---------------------------------------------------------------------------
// Prep kernels
// ---------------------------------------------------------------------------
__global__ __launch_bounds__(256)
void wcat_split_kernel(const float* __restrict__ w_ih, const float* __restrict__ w_hh,
                       u16* __restrict__ dh, u16* __restrict__ dl)
{
    int col = blockIdx.x * 256 + threadIdx.x;
    int n = blockIdx.y;
    if (col >= KCAT) return;
    float v = 0.f;
    if (col < E)          v = w_ih[(size_t)n * E + col];
    else if (col >= EPAD) v = w_hh[(size_t)n * H + (col - EPAD)];
    u16 hi = f2bf(v);
    dh[(size_t)n * KCAT + col] = hi;
    dl[(size_t)n * KCAT + col] = f2bf(v - bf2f(hi));
}

// dst[n][k] = split(src[k][n]) for H x H weights (wy, wh).
__global__ __launch_bounds__(256)
void tsplit_kernel(const float* __restrict__ src, u16* __restrict__ dh, u16* __restrict__ dl)
{
    int k = blockIdx.x * 256 + threadIdx.x;
    int n = blockIdx.y;
    float v = src[(size_t)k * H + n];
    u16 hi = f2bf(v);
    dh[(size_t)n * H + k] = hi;
    dl[(size_t)n * H + k] = f2bf(v - bf2f(hi));
}

// [wr | wt] transposed-split: dst[n][k], n<H -> wr[k][n], else wt[k][n-H].
__global__ __launch_bounds__(256)
void wrt_split_kernel(const float* __restrict__ wr, const float* __restrict__ wt,
                      u16* __restrict__ dh, u16* __restrict__ dl)
{
    int k = blockIdx.x * 256 + threadIdx.x;    // 0..H-1
    int n = blockIdx.y;                        // 0..2047
    float v = (n < H) ? wr[(size_t)k * H + n] : wt[(size_t)k * H + (n - H)];
    u16 hi = f2bf(v);
    dh[(size_t)n * H + k] = hi;
    dl[(size_t)n * H + k] = f2bf(v - bf2f(hi));
}

// ---------------------------------------------------------------------------
// Persistent LSTM scan. 256 blocks x 256 thr. Block: bx = k-tile (16 units),
// by = m-quarter (32 rows). Wave g owns gate g: weights resident (AGPR/VGPR).
// Per step: emb MFMAs (h-independent) -> gbar_wait -> h MFMAs -> epilogue ->
// gbar_arrive.
// ---------------------------------------------------------------------------
template<int PREMISE>
__global__ __launch_bounds__(256, 1)
void lstm_scan(const int* __restrict__ toks, int S,
               const float* __restrict__ emb,
               const u16* __restrict__ Wh, const u16* __restrict__ Wl,
               const float* __restrict__ b_ih, const float* __restrict__ b_hh,
               u16* __restrict__ h0h, u16* __restrict__ h0l,
               u16* __restrict__ h1h, u16* __restrict__ h1l,
               float* __restrict__ c, float* __restrict__ hmask,
               float* __restrict__ cmask,
               u16* __restrict__ seq_hi, u16* __restrict__ seq_lo,
               int* __restrict__ bar)
{
    const int tid  = threadIdx.x;
    const int lane = tid & 63;
    const int g    = tid >> 6;           // gate = wave
    const int l15  = lane & 15;
    const int lk8  = (lane >> 4) * 8;
    const int bx   = blockIdx.x & 63;
    const int by   = blockIdx.x >> 6;    // 0..3
    const int k0   = bx * 16;
    const int m0   = by * 32;

    // ---- resident weights: rows n = g*H + k0 + l15, cols ks*32 + lk8 ----
    bf16x8 wh_r[42], wl_r[42];
    {
        const u16* ph = Wh + (size_t)(g * H + k0 + l15) * KCAT + lk8;
        const u16* pl = Wl + (size_t)(g * H + k0 + l15) * KCAT + lk8;
#pragma unroll
        for (int ks = 0; ks < 42; ++ks) {
            wh_r[ks] = *(const bf16x8*)(ph + ks * 32);
            wl_r[ks] = *(const bf16x8*)(pl + ks * 32);
        }
    }
    const int ke = k0 + (tid & 15);
    const float bs0 = b_ih[0 * H + ke] + b_hh[0 * H + ke];
    const float bs1 = b_ih[1 * H + ke] + b_hh[1 * H + ke];
    const float bs2 = b_ih[2 * H + ke] + b_hh[2 * H + ke];
    const float bs3 = b_ih[3 * H + ke] + b_hh[3 * H + ke];

    __shared__ float gt[4][32][17];

    for (int t = 0; t < S; ++t) {
        const u16* hinh = (t & 1) ? h1h : h0h;
        const u16* hinl = (t & 1) ? h1l : h0l;
        u16* houth = (t & 1) ? h0h : h1h;
        u16* houtl = (t & 1) ? h0l : h1l;

        const float* ea[2];
#pragma unroll
        for (int mt = 0; mt < 2; ++mt) {
            int row = m0 + mt * 16 + l15;
            int tok = toks[row * S + t];
            ea[mt] = emb + (size_t)tok * E + lk8;
        }

        f32x4 acc[2] = {{0.f,0.f,0.f,0.f},{0.f,0.f,0.f,0.f}};

        // ---- emb segment (no dependence on previous step's h) ----
        // ks 0..8: max col = 8*32 + 24 + 7 = 287 < 300 -> unguarded loads.
#pragma unroll
        for (int ks = 0; ks < 9; ++ks) {
#pragma unroll
            for (int mt = 0; mt < 2; ++mt) {
                float4 f0 = *(const float4*)(ea[mt] + ks * 32);
                float4 f1 = *(const float4*)(ea[mt] + ks * 32 + 4);
                float v[8] = {f0.x, f0.y, f0.z, f0.w, f1.x, f1.y, f1.z, f1.w};
                bf16x8 a_hi, a_lo;
#pragma unroll
                for (int j = 0; j < 8; ++j) {
                    u16 hi = f2bf(v[j]);
                    a_hi[j] = (short)hi;
                    a_lo[j] = (short)f2bf(v[j] - bf2f(hi));
                }
                acc[mt] = mfma16(a_hi, wh_r[ks], acc[mt]);
                acc[mt] = mfma16(a_lo, wh_r[ks], acc[mt]);
                acc[mt] = mfma16(a_hi, wl_r[ks], acc[mt]);
            }
        }
        {   // ks = 9: cols 288 + lk8 + j, guard k < E (weight pad cols are 0)
#pragma unroll
            for (int mt = 0; mt < 2; ++mt) {
                float v[8];
#pragma unroll
                for (int j = 0; j < 8; ++j) {
                    int k = 288 + lk8 + j;
                    v[j] = (k < E) ? ea[mt][k - lk8] : 0.f;
                }
                bf16x8 a_hi, a_lo;
#pragma unroll
                for (int j = 0; j < 8; ++j) {
                    u16 hi = f2bf(v[j]);
                    a_hi[j] = (short)hi;
                    a_lo[j] = (short)f2bf(v[j] - bf2f(hi));
                }
                acc[mt] = mfma16(a_hi, wh_r[9], acc[mt]);
                acc[mt] = mfma16(a_lo, wh_r[9], acc[mt]);
                acc[mt] = mfma16(a_hi, wl_r[9], acc[mt]);
            }
        }

        // ---- wait for previous step's h (overlapped with emb work above) ----
        if (t > 0) gbar_wait(bar, t * NB_L);

        const u16* ah = hinh + (size_t)(m0 + l15) * H + lk8;
        const ptrdiff_t dH = hinl - hinh;

        // h segment: ks 0..31 (weight cols 320..1343)
#pragma unroll
        for (int ks = 0; ks < 32; ++ks) {
#pragma unroll
            for (int mt = 0; mt < 2; ++mt) {
                const u16* p = ah + mt * 16 * H + ks * 32;
                bf16x8 a_hi = *(const bf16x8*)(p);
                bf16x8 a_lo = *(const bf16x8*)(p + dH);
                acc[mt] = mfma16(a_hi, wh_r[10 + ks], acc[mt]);
                acc[mt] = mfma16(a_lo, wh_r[10 + ks], acc[mt]);
                acc[mt] = mfma16(a_hi, wl_r[10 + ks], acc[mt]);
            }
        }

        // ---- gate exchange via LDS ----
#pragma unroll
        for (int mt = 0; mt < 2; ++mt)
#pragma unroll
            for (int j = 0; j < 4; ++j)
                gt[g][mt * 16 + (lane >> 4) * 4 + j][l15] = acc[mt][j];
        __syncthreads();

        // ---- cell epilogue: 2 (m, ke) elements per thread ----
#pragma unroll
        for (int i = 0; i < 2; ++i) {
            int ml = (tid >> 4) + i * 16;        // 0..31
            int m  = m0 + ml;
            size_t idx = (size_t)m * H + ke;
            float gi = gt[0][ml][tid & 15] + bs0;
            float gf = gt[1][ml][tid & 15] + bs1;
            float gg = gt[2][ml][tid & 15] + bs2;
            float go = gt[3][ml][tid & 15] + bs3;
            float c2 = sigf(gf) * c[idx] + sigf(gi) * tanh_fast(gg);
            float h2 = sigf(go) * tanh_fast(c2);
            c[idx] = c2;
            u16 hh = f2bf(h2);
            houth[idx] = hh;
            houtl[idx] = f2bf(h2 - bf2f(hh));
            float mk = (toks[m * S + t] != 0) ? 1.f : 0.f;
            float hmv = mk * h2 + (1.f - mk) * hmask[idx];
            hmask[idx] = hmv;
            u16 mh = f2bf(hmv);
            u16 mlv = f2bf(hmv - bf2f(mh));
            if (PREMISE) {
                float cmv = mk * c2 + (1.f - mk) * cmask[idx];
                cmask[idx] = cmv;
                size_t yi = ((size_t)m * SP + t) * H + ke;   // Y [B][SP][H]
                seq_hi[yi] = mh; seq_lo[yi] = mlv;
            } else {
                size_t oi = ((size_t)t * B + m) * H + ke;    // outh [SH][B][H]
                seq_hi[oi] = mh; seq_lo[oi] = mlv;
            }
        }
        if (t + 1 < S) gbar_arrive(bar);
    }
}

// ---------------------------------------------------------------------------
// Persistent attention scan. 128 blocks x 256 thr; block = batch row b.
// Per t: phase A srt = r_s @ WrtT (grid-wide wave tiling), barrier,
// phase B scores (s in LDS) + phase C softmax + r update, barrier.
// ---------------------------------------------------------------------------
__global__ __launch_bounds__(256, 1)
void attn_scan(const u16* __restrict__ firstH, const u16* __restrict__ firstL, // [B*SP][H]
               const u16* __restrict__ hsecH, const u16* __restrict__ hsecL,   // [SH*B][H]
               const u16* __restrict__ Wrth, const u16* __restrict__ Wrtl,     // [2048][1024]
               const u16* __restrict__ Yh, const u16* __restrict__ Yl,         // [B*SP][H]
               const float* __restrict__ wv,      // [H]
               const int* __restrict__ ptoks, const int* __restrict__ htoks,
               float* __restrict__ srt,           // [B][2048] (secr | rwt)
               u16* __restrict__ rh, u16* __restrict__ rl,  // [B][H] split r
               float* __restrict__ r,             // [B][H] fp32
               int* __restrict__ bar)
{
    const int tid  = threadIdx.x;
    const int lane = tid & 63;
    const int w    = tid >> 6;
    const int l15  = lane & 15;
    const int lk8  = (lane >> 4) * 8;
    const int b    = blockIdx.x;

    __shared__ float sArr[SP];
    __shared__ float al[SP];
    __shared__ float red[SP];

    // hoisted: per-lane wv slice for score dot
    float wv_e[16];
#pragma unroll
    for (int e = 0; e < 16; ++e) wv_e[e] = wv[lane + e * 64];

    // phase-A tile assignment: 512 waves x 2 n-tiles = 128 n-tiles x 8 m-tiles
    const int gw  = blockIdx.x * 4 + w;
    const int n0  = (gw & 63) * 32;          // two adjacent 16-col tiles
    const int pm0 = (gw >> 6) * 16;          // 16 batch rows
    const ptrdiff_t dA = rl - rh;
    const ptrdiff_t dB = Wrtl - Wrth;

    int tgt = 0;
    for (int t = 0; t < SH; ++t) {
        // ---- phase A: srt[m][n] for n in {n0, n0+16} ----
        {
            const u16* ap  = rh + (size_t)(pm0 + l15) * H + lk8;
            const u16* bp0 = Wrth + (size_t)(n0 + l15) * H + lk8;
            const u16* bp1 = Wrth + (size_t)(n0 + 16 + l15) * H + lk8;
            f32x4 a0 = {0.f,0.f,0.f,0.f}, a1 = {0.f,0.f,0.f,0.f};
#pragma unroll 4
            for (int ks = 0; ks < 32; ++ks) {
                bf16x8 ahi = *(const bf16x8*)(ap + ks * 32);
                bf16x8 alo = *(const bf16x8*)(ap + dA + ks * 32);
                bf16x8 b0h = *(const bf16x8*)(bp0 + ks * 32);
                bf16x8 b0l = *(const bf16x8*)(bp0 + dB + ks * 32);
                a0 = mfma16(ahi, b0h, a0);
                a0 = mfma16(alo, b0h, a0);
                a0 = mfma16(ahi, b0l, a0);
                bf16x8 b1h = *(const bf16x8*)(bp1 + ks * 32);
                bf16x8 b1l = *(const bf16x8*)(bp1 + dB + ks * 32);
                a1 = mfma16(ahi, b1h, a1);
                a1 = mfma16(alo, b1h, a1);
                a1 = mfma16(ahi, b1l, a1);
            }
#pragma unroll
            for (int j = 0; j < 4; ++j) {
                int mrow = pm0 + (lane >> 4) * 4 + j;
                srt[(size_t)mrow * 2048 + n0 + l15]      = a0[j];
                srt[(size_t)mrow * 2048 + n0 + 16 + l15] = a1[j];
            }
        }
        tgt += NB_A;
        gbar_arrive(bar);
        gbar_wait(bar, tgt);

        // ---- phase B: scores for this block's b; s stays in LDS ----
        {
            float hsum[16];
            const u16* hbh = hsecH + ((size_t)t * B + b) * H;
            const u16* hbl = hsecL + ((size_t)t * B + b) * H;
            const float* sb = srt + (size_t)b * 2048;
#pragma unroll
            for (int e = 0; e < 16; ++e) {
                int hh = lane + e * 64;
                hsum[e] = bf2f(hbh[hh]) + bf2f(hbl[hh]) + sb[hh];
            }
            for (int pp = 0; pp < 32; ++pp) {
                int p = w * 32 + pp;
                const u16* fph = firstH + ((size_t)b * SP + p) * H;
                const u16* fpl = firstL + ((size_t)b * SP + p) * H;
                float acc = 0.f;
#pragma unroll
                for (int e = 0; e < 16; ++e) {
                    int hh = lane + e * 64;
                    acc += tanh_fast(bf2f(fph[hh]) + bf2f(fpl[hh]) + hsum[e]) * wv_e[e];
                }
#pragma unroll
                for (int off = 32; off; off >>= 1) acc += __shfl_xor(acc, off);
                if (lane == 0)
                    sArr[p] = acc + ((ptoks[b * SP + p] != 0) ? 0.f : -1000.f);
            }
        }
        __syncthreads();

        // ---- phase C: softmax + r_t = alpha@Y + tanh(rwt); masked carry ----
        {
            if (tid < SP) { float v = sArr[tid]; al[tid] = v; red[tid] = v; }
            __syncthreads();
            for (int off = 64; off; off >>= 1) {
                if (tid < off) red[tid] = fmaxf(red[tid], red[tid + off]);
                __syncthreads();
            }
            float mx = red[0];
            __syncthreads();
            if (tid < SP) { float e = __expf(al[tid] - mx); al[tid] = e; red[tid] = e; }
            __syncthreads();
            for (int off = 64; off; off >>= 1) {
                if (tid < off) red[tid] += red[tid + off];
                __syncthreads();
            }
            float inv = 1.f / red[0];
            __syncthreads();
            if (tid < SP) al[tid] *= inv;
            __syncthreads();

            const int h0 = tid * 4;
            float a0 = 0.f, a1 = 0.f, a2 = 0.f, a3 = 0.f;
            const u16* yhp = Yh + (size_t)b * SP * H + h0;
            const u16* ylp = Yl + (size_t)b * SP * H + h0;
#pragma unroll 2
            for (int p = 0; p < SP; ++p) {
                float a = al[p];
                uint2 vh = *(const uint2*)(yhp + (size_t)p * H);
                uint2 vl = *(const uint2*)(ylp + (size_t)p * H);
                a0 += a * (__uint_as_float(vh.x << 16) + __uint_as_float(vl.x << 16));
                a1 += a * (__uint_as_float(vh.x & 0xffff0000u) + __uint_as_float(vl.x & 0xffff0000u));
                a2 += a * (__uint_as_float(vh.y << 16) + __uint_as_float(vl.y << 16));
                a3 += a * (__uint_as_float(vh.y & 0xffff0000u) + __uint_as_float(vl.y & 0xffff0000u));
            }
            float mk = (htoks[b * SH + t] != 0) ? 1.f : 0.f;
            const float* rwt = srt + (size_t)b * 2048 + H;
            float4 ro = *(const float4*)(r + (size_t)b * H + h0);
            float rn0 = a0 + tanh_fast(rwt[h0 + 0]);
            float rn1 = a1 + tanh_fast(rwt[h0 + 1]);
            float rn2 = a2 + tanh_fast(rwt[h0 + 2]);
            float rn3 = a3 + tanh_fast(rwt[h0 + 3]);
            float4 rv;
            rv.x = mk * rn0 + (1.f - mk) * ro.x;
            rv.y = mk * rn1 + (1.f - mk) * ro.y;
            rv.z = mk * rn2 + (1.f - mk) * ro.z;
            rv.w = mk * rn3 + (1.f - mk) * ro.w;
            *(float4*)(r + (size_t)b * H + h0) = rv;
            u16 q0 = f2bf(rv.x), q1 = f2bf(rv.y), q2 = f2bf(rv.z), q3 = f2bf(rv.w);
            ushort4 sh = make_ushort4(q0, q1, q2, q3);
            ushort4 sl = make_ushort4(f2bf(rv.x - bf2f(q0)), f2bf(rv.y - bf2f(q1)),
                                      f2bf(rv.z - bf2f(q2)), f2bf(rv.w - bf2f(q3)));
            *(ushort4*)(rh + (size_t)b * H + h0) = sh;
            *(ushort4*)(rl + (size_t)b * H + h0) = sl;
        }
        if (t + 1 < SH) {
            tgt += NB_A;
            gbar_arrive(bar);
            gbar_wait(bar, tgt);
        }
    }
}

// ---------------------------------------------------------------------------
// Split-bf16 MFMA GEMM: C = A[M,K] @ B^T, B stored [N][K] hi/lo.
// SPLITOUT: write C as split bf16 hi/lo (u16) instead of fp32.
// ---------------------------------------------------------------------------
template<bool SPLITOUT>
__global__ __launch_bounds__(256)
void gemm_mfma_kernel(const u16* __restrict__ Ah, const u16* __restrict__ Al,
                      const u16* __restrict__ Bh, const u16* __restrict__ Bl,
                      float* __restrict__ C, u16* __restrict__ Ch, u16* __restrict__ Cl,
                      int M, int N, int K)
{
    const int tid  = threadIdx.x;
    const int lane = tid & 63;
    const int wave = tid >> 6;
    const int l15  = lane & 15;
    const int lk8  = (lane >> 4) * 8;
    const int m0   = blockIdx.y * 64 + wave * 16;
    const int n0   = blockIdx.x * 64;

    const u16* ahp = Ah + (size_t)(m0 + l15) * K + lk8;
    const u16* alp = Al + (size_t)(m0 + l15) * K + lk8;
    const u16* bhp[4]; const u16* blp[4];
#pragma unroll
    for (int nt = 0; nt < 4; ++nt) {
        size_t o = (size_t)(n0 + nt * 16 + l15) * K + lk8;
        bhp[nt] = Bh + o; blp[nt] = Bl + o;
    }
    f32x4 acc[4] = {{0.f,0.f,0.f,0.f},{0.f,0.f,0.f,0.f},
                    {0.f,0.f,0.f,0.f},{0.f,0.f,0.f,0.f}};
    const int nks = K >> 5;
#pragma unroll 2
    for (int ks = 0; ks < nks; ++ks) {
        bf16x8 a_hi = *(const bf16x8*)(ahp + ks * 32);
        bf16x8 a_lo = *(const bf16x8*)(alp + ks * 32);
#pragma unroll
        for (int nt = 0; nt < 4; ++nt) {
            bf16x8 b_hi = *(const bf16x8*)(bhp[nt] + ks * 32);
            bf16x8 b_lo = *(const bf16x8*)(blp[nt] + ks * 32);
            acc[nt] = mfma16(a_hi, b_hi, acc[nt]);
            acc[nt] = mfma16(a_lo, b_hi, acc[nt]);
            acc[nt] = mfma16(a_hi, b_lo, acc[nt]);
        }
    }
#pragma unroll
    for (int nt = 0; nt < 4; ++nt)
#pragma unroll
        for (int j = 0; j < 4; ++j) {
            int m = m0 + (lane >> 4) * 4 + j;
            size_t idx = (size_t)m * N + n0 + nt * 16 + l15;
            if (SPLITOUT) {
                float v = acc[nt][j];
                u16 hi = f2bf(v);
                Ch[idx] = hi;
                Cl[idx] = f2bf(v - bf2f(hi));
            } else {
                C[idx] = acc[nt][j];
            }
        }
}

// ---------------------------------------------------------------------------
// Skinny fp32 GEMM (M=128): tile 32x64, BK=16, 256 thr, dbuf (verified).
// ---------------------------------------------------------------------------
template<bool ACC>
__global__ __launch_bounds__(256)
void skinny_kernel(const float* __restrict__ A,
                   const float* __restrict__ B1, float* __restrict__ C1,
                   const float* __restrict__ B2, float* __restrict__ C2,
                   int K, int N, int ntiles)
{
    const int tid = threadIdx.x;
    const int tx = tid & 15, ty = tid >> 4;
    const int bx = blockIdx.x;
    const float* Bw = (bx < ntiles) ? B1 : B2;
    float* C       = (bx < ntiles) ? C1 : C2;
    const int n0 = ((bx < ntiles) ? bx : bx - ntiles) * 64;
    const int m0 = blockIdx.y * 32;

    __shared__ float As[2][16][34];
    __shared__ float Bs[2][16][68];
    const int sq = tid & 15, sm = tid >> 4;
    const int nb = tid & 63, kb = tid >> 6;

    float ra[2], rb[4];
    auto ldA = [&](int k0, int rr) -> float {
        return A[(size_t)(m0 + sm + 16 * rr) * K + k0 + sq];
    };
    auto ldB = [&](int k0, int rr) -> float {
        return Bw[(size_t)(k0 + kb + 4 * rr) * N + n0 + nb];
    };

    float acc[2][4] = {};
    ra[0] = ldA(0, 0); ra[1] = ldA(0, 1);
#pragma unroll
    for (int rr = 0; rr < 4; ++rr) rb[rr] = ldB(0, rr);
    As[0][sq][sm] = ra[0]; As[0][sq][sm + 16] = ra[1];
#pragma unroll
    for (int rr = 0; rr < 4; ++rr) Bs[0][kb + 4 * rr][nb] = rb[rr];
    __syncthreads();

    const int NKT = K / 16;
    for (int kt = 0; kt < NKT; ++kt) {
        const int buf = kt & 1;
        if (kt + 1 < NKT) {
            int k0 = (kt + 1) * 16;
            ra[0] = ldA(k0, 0); ra[1] = ldA(k0, 1);
#pragma unroll
            for (int rr = 0; rr < 4; ++rr) rb[rr] = ldB(k0, rr);
        }
#pragma unroll
        for (int qq = 0; qq < 16; ++qq) {
            float2 a2 = *(const float2*)&As[buf][qq][ty * 2];
            float4 b4 = *(const float4*)&Bs[buf][qq][tx * 4];
            acc[0][0] += a2.x * b4.x; acc[0][1] += a2.x * b4.y;
            acc[0][2] += a2.x * b4.z; acc[0][3] += a2.x * b4.w;
            acc[1][0] += a2.y * b4.x; acc[1][1] += a2.y * b4.y;
            acc[1][2] += a2.y * b4.z; acc[1][3] += a2.y * b4.w;
        }
        if (kt + 1 < NKT) {
            const int nbuf = buf ^ 1;
            As[nbuf][sq][sm] = ra[0]; As[nbuf][sq][sm + 16] = ra[1];
#pragma unroll
            for (int rr = 0; rr < 4; ++rr) Bs[nbuf][kb + 4 * rr][nb] = rb[rr];
            __syncthreads();
        }
    }
#pragma unroll
    for (int i = 0; i < 2; ++i) {
        int m = m0 + ty * 2 + i;
        float* cp = &C[(size_t)m * N + n0 + tx * 4];
        float4 v = make_float4(acc[i][0], acc[i][1], acc[i][2], acc[i][3]);
        if (ACC) {
            float4 o = *(const float4*)cp;
            v.x += o.x; v.y += o.y; v.z += o.z; v.w += o.w;
        }
        *(float4*)cp = v;
    }
}

// logits -> softmax over 4 classes
__global__ __launch_bounds__(256)
void final_kernel(const float* __restrict__ pre,
                  const float* __restrict__ fc_w,
                  const float* __restrict__ fc_b,
                  float* __restrict__ out)
{
    int b = blockIdx.x;
    float acc[NC] = {0.f, 0.f, 0.f, 0.f};
    for (int k = threadIdx.x; k < H; k += 256) {
        float hs = tanh_fast(pre[(size_t)b * H + k]);
#pragma unroll
        for (int cc = 0; cc < NC; ++cc) acc[cc] += hs * fc_w[cc * H + k];
    }
    __shared__ float red[NC][256];
#pragma unroll
    for (int cc = 0; cc < NC; ++cc) red[cc][threadIdx.x] = acc[cc];
    __syncthreads();
    for (int off = 128; off > 0; off >>= 1) {
        if (threadIdx.x < off)
#pragma unroll
            for (int cc = 0; cc < NC; ++cc)
                red[cc][threadIdx.x] += red[cc][threadIdx.x + off];
        __syncthreads();
    }
    if (threadIdx.x == 0) {
        float l[NC], mx = -1e30f;
#pragma unroll
        for (int cc = 0; cc < NC; ++cc) { l[cc] = red[cc][0] + fc_b[cc]; mx = fmaxf(mx, l[cc]); }
        float sum = 0.f;
#pragma unroll
        for (int cc = 0; cc < NC; ++cc) { l[cc] = __expf(l[cc] - mx); sum += l[cc]; }
#pragma unroll
        for (int cc = 0; cc < NC; ++cc) out[b * NC + cc] = l[cc] / sum;
    }
}

extern "C" void kernel_launch(void* const* d_in, const int* in_sizes, int n_in,
                              void* d_out, int out_size, void* d_ws, size_t ws_size,
                              hipStream_t stream)
{
    const int*   prem   = (const int*)d_in[0];
    const int*   hyp    = (const int*)d_in[1];
    const float* emb    = (const float*)d_in[2];
    const float* w_ih_p = (const float*)d_in[3];
    const float* w_hh_p = (const float*)d_in[4];
    const float* b_ih_p = (const float*)d_in[5];
    const float* b_hh_p = (const float*)d_in[6];
    const float* w_ih_h = (const float*)d_in[7];
    const float* w_hh_h = (const float*)d_in[8];
    const float* b_ih_h = (const float*)d_in[9];
    const float* b_hh_h = (const float*)d_in[10];
    const float* wy     = (const float*)d_in[11];
    const float* wh     = (const float*)d_in[12];
    const float* wr     = (const float*)d_in[13];
    const float* wv     = (const float*)d_in[14];
    const float* wt     = (const float*)d_in[15];
    const float* wp     = (const float*)d_in[16];
    const float* wx     = (const float*)d_in[17];
    const float* fc_w   = (const float*)d_in[18];
    const float* fc_b   = (const float*)d_in[19];
    float* out = (float*)d_out;
    (void)in_sizes; (void)n_in; (void)out_size; (void)ws_size;

    char* wsc = (char*)d_ws;
    size_t off = 0;
    auto alloc = [&](size_t bytes) -> void* {
        void* p = wsc + off;
        off += (bytes + 255) & ~(size_t)255;
        return p;
    };
    // split weight packs (~44 MB)
    u16* Wp_hi  = (u16*)alloc((size_t)G4H * KCAT * 2);
    u16* Wp_lo  = (u16*)alloc((size_t)G4H * KCAT * 2);
    u16* Wq_hi  = (u16*)alloc((size_t)G4H * KCAT * 2);
    u16* Wq_lo  = (u16*)alloc((size_t)G4H * KCAT * 2);
    u16* wyT_hi = (u16*)alloc((size_t)H * H * 2);
    u16* wyT_lo = (u16*)alloc((size_t)H * H * 2);
    u16* whT_hi = (u16*)alloc((size_t)H * H * 2);
    u16* whT_lo = (u16*)alloc((size_t)H * H * 2);
    u16* WrtH   = (u16*)alloc((size_t)2 * H * H * 2);
    u16* WrtL   = (u16*)alloc((size_t)2 * H * H * 2);
    // sequence outputs + hoisted GEMM outputs, all split bf16 (~151 MB)
    u16* Y_hi   = (u16*)alloc((size_t)B * SP * H * 2);
    u16* Y_lo   = (u16*)alloc((size_t)B * SP * H * 2);
    u16* OH_hi  = (u16*)alloc((size_t)SH * B * H * 2);
    u16* OH_lo  = (u16*)alloc((size_t)SH * B * H * 2);
    u16* firstH = (u16*)alloc((size_t)B * SP * H * 2);
    u16* firstL = (u16*)alloc((size_t)B * SP * H * 2);
    u16* hsecH  = (u16*)alloc((size_t)SH * B * H * 2);
    u16* hsecL  = (u16*)alloc((size_t)SH * B * H * 2);
    // h ping-pong (split) — contiguous for one memset
    const size_t BH = (size_t)B * H;
    u16* h0h = (u16*)alloc(BH * 2);
    u16* h0l = (u16*)alloc(BH * 2);
    u16* h1h = (u16*)alloc(BH * 2);
    u16* h1l = (u16*)alloc(BH * 2);
    // c, hm, cm contiguous for one memset
    float* cbuf = (float*)alloc(BH * 4);
    float* hm   = (float*)alloc(BH * 4);
    float* cm   = (float*)alloc(BH * 4);
    float* r    = (float*)alloc(BH * 4);
    u16*   rh   = (u16*)alloc(BH * 2);
    u16*   rl   = (u16*)alloc(BH * 2);
    float* srt  = (float*)alloc((size_t)B * 2048 * 4);
    float* pre  = (float*)alloc(BH * 4);
    int*   bars = (int*)alloc(256);
    int* barP = bars + 0; int* barH = bars + 16; int* barA = bars + 32;

    // -------- one-time splits --------
    dim3 gW((KCAT + 255) / 256, G4H);
    wcat_split_kernel<<<gW, 256, 0, stream>>>(w_ih_p, w_hh_p, Wp_hi, Wp_lo);
    wcat_split_kernel<<<gW, 256, 0, stream>>>(w_ih_h, w_hh_h, Wq_hi, Wq_lo);
    tsplit_kernel<<<dim3(H / 256, H), 256, 0, stream>>>(wy, wyT_hi, wyT_lo);
    tsplit_kernel<<<dim3(H / 256, H), 256, 0, stream>>>(wh, whT_hi, whT_lo);
    wrt_split_kernel<<<dim3(H / 256, 2 * H), 256, 0, stream>>>(wr, wt, WrtH, WrtL);

    hipMemsetAsync(h0h, 0, 4 * BH * 2, stream);   // h0h,h0l,h1h,h1l
    hipMemsetAsync(cbuf, 0, 3 * BH * 4, stream);  // c, hm, cm
    hipMemsetAsync(r, 0, BH * 4, stream);
    hipMemsetAsync(rh, 0, 2 * BH * 2, stream);    // rh, rl
    hipMemsetAsync(bars, 0, 256, stream);

    // -------- premise LSTM (persistent) --------
    lstm_scan<1><<<NB_L, 256, 0, stream>>>(
        prem, SP, emb, Wp_hi, Wp_lo, b_ih_p, b_hh_p,
        h0h, h0l, h1h, h1l, cbuf, hm, cm, Y_hi, Y_lo, barP);

    // -------- hypothesis LSTM: h=0, c = cm --------
    hipMemsetAsync(h0h, 0, 4 * BH * 2, stream);
    hipMemsetAsync(hm, 0, BH * 4, stream);
    lstm_scan<0><<<NB_L, 256, 0, stream>>>(
        hyp, SH, emb, Wq_hi, Wq_lo, b_ih_h, b_hh_h,
        h0h, h0l, h1h, h1l, cm, hm, (float*)nullptr, OH_hi, OH_lo, barH);
    // hm = out_h_last

    // -------- hoisted GEMMs (split-in, split-out) --------
    gemm_mfma_kernel<true><<<dim3(H / 64, (B * SP) / 64), 256, 0, stream>>>(
        Y_hi, Y_lo, wyT_hi, wyT_lo, nullptr, firstH, firstL, B * SP, H, H);
    gemm_mfma_kernel<true><<<dim3(H / 64, (SH * B) / 64), 256, 0, stream>>>(
        OH_hi, OH_lo, whT_hi, whT_lo, nullptr, hsecH, hsecL, SH * B, H, H);

    // -------- attention scan (persistent) --------
    attn_scan<<<NB_A, 256, 0, stream>>>(
        firstH, firstL, hsecH, hsecL, WrtH, WrtL, Y_hi, Y_lo, wv, prem, hyp,
        srt, rh, rl, r, barA);

    // -------- final projection + softmax --------
    skinny_kernel<false><<<dim3(16, 4), 256, 0, stream>>>(r,  wp, pre, nullptr, nullptr, H, H, 16);
    skinny_kernel<true ><<<dim3(16, 4), 256, 0, stream>>>(hm, wx, pre, nullptr, nullptr, H, H, 16);
    final_kernel<<<B, 256, 0, stream>>>(pre, fc_w, fc_b, out);
}

// Round 5
// 13917.213 us; speedup vs baseline: 1.9282x; 1.7460x over previous
//
#include <hip/hip_runtime.h>

// SNLI attention-LSTM, MI355X. Round 5: fence-free flag barrier + coherent-
// point (sc0sc1) shared state. R4 showed barriers still ~70us/step: arrival
// RMWs on one line serialize (~256 x 250ns) and __threadfence emits L2
// writeback/invalidate per block. Changes:
//  - all-to-all flag barrier: arrive = relaxed agent atomic STORE to own flag
//    (no shared-line RMW), wait = poll own lane's flag + __syncthreads_and.
//    No threadfence anywhere in the persistent kernels.
//  - ALL cross-block state (lstm h ping-pong, attn srt + r) accessed via
//    relaxed agent-scope atomics (write-through coherence point). h and r are
//    PACKED u32 (bf16hi<<16 | bf16lo), cooperatively staged into LDS once per
//    block per step (kills the 4-wave redundancy bypass loads would cause).
//  - weights/emb/Y/first/Wrt stay normally cached (read-only or private).

using u16 = unsigned short;
using u32 = unsigned int;
using u64 = unsigned long long;
typedef short bf16x8 __attribute__((ext_vector_type(8)));
typedef float f32x4 __attribute__((ext_vector_type(4)));

constexpr int B  = 128;
constexpr int SP = 128;
constexpr int SH = 64;
constexpr int H  = 1024;
constexpr int E  = 300;
constexpr int NC = 4;
constexpr int G4H  = 4 * H;          // 4096
constexpr int EPAD = 320;            // E padded to multiple of 32
constexpr int KCAT = EPAD + H;       // 1344
constexpr int NB_L = 256;            // lstm persistent blocks (== CU count)
constexpr int NB_A = 128;            // attn persistent blocks

__device__ __forceinline__ float sigf(float x) { return 1.0f / (1.0f + __expf(-x)); }
__device__ __forceinline__ float tanh_fast(float x) {
    float e = __expf(2.0f * x);
    return 1.0f - 2.0f / (e + 1.0f);
}
__device__ __forceinline__ u16 f2bf(float x) {           // round-to-nearest-even
    union { float f; unsigned u; } v; v.f = x;
    unsigned r = v.u + 0x7fffu + ((v.u >> 16) & 1u);
    return (u16)(r >> 16);
}
__device__ __forceinline__ float bf2f(u16 h) {
    union { unsigned u; float f; } v; v.u = ((unsigned)h) << 16;
    return v.f;
}
__device__ __forceinline__ f32x4 mfma16(bf16x8 a, bf16x8 b, f32x4 c) {
    return __builtin_amdgcn_mfma_f32_16x16x32_bf16(a, b, c, 0, 0, 0);
}
// pack fp32 -> (bf16 hi << 16) | bf16 lo
__device__ __forceinline__ u32 packhl(float v) {
    u16 hi = f2bf(v);
    u16 lo = f2bf(v - bf2f(hi));
    return ((u32)hi << 16) | lo;
}

// ---- coherent-point (agent scope, relaxed) accessors ----
__device__ __forceinline__ u64 aLd64(const u64* p) {
    return __hip_atomic_load(p, __ATOMIC_RELAXED, __HIP_MEMORY_SCOPE_AGENT);
}
__device__ __forceinline__ float aLdF(const float* p) {
    return __hip_atomic_load(p, __ATOMIC_RELAXED, __HIP_MEMORY_SCOPE_AGENT);
}
__device__ __forceinline__ void aStF(float* p, float v) {
    __hip_atomic_store(p, v, __ATOMIC_RELAXED, __HIP_MEMORY_SCOPE_AGENT);
}
__device__ __forceinline__ void aSt32(u32* p, u32 v) {
    __hip_atomic_store(p, v, __ATOMIC_RELAXED, __HIP_MEMORY_SCOPE_AGENT);
}
__device__ __forceinline__ void aSt64(u64* p, u64 v) {
    __hip_atomic_store(p, v, __ATOMIC_RELAXED, __HIP_MEMORY_SCOPE_AGENT);
}

// ---- all-to-all flag barrier (no RMW, no cache-flush fences) ----
__device__ __forceinline__ void flag_arrive(int* flags, int epoch) {
    asm volatile("s_waitcnt vmcnt(0)" ::: "memory");   // this wave's stores done
    __syncthreads();                                   // all waves done
    if (threadIdx.x == 0)
        __hip_atomic_store(&flags[blockIdx.x], epoch,
                           __ATOMIC_RELAXED, __HIP_MEMORY_SCOPE_AGENT);
}
__device__ __forceinline__ void flag_wait(int* flags, int n, int epoch) {
    for (;;) {
        int v = (threadIdx.x < n)
            ? __hip_atomic_load(&flags[threadIdx.x], __ATOMIC_RELAXED,
                                __HIP_MEMORY_SCOPE_AGENT)
            : epoch;
        if (__syncthreads_and(v >= epoch)) break;
        __builtin_amdgcn_s_sleep(8);
    }
    __builtin_amdgcn_sched_barrier(0);
}

// ---------------------------------------------------------------------------
// Prep kernels
// ---------------------------------------------------------------------------
__global__ __launch_bounds__(256)
void wcat_split_kernel(const float* __restrict__ w_ih, const float* __restrict__ w_hh,
                       u16* __restrict__ dh, u16* __restrict__ dl)
{
    int col = blockIdx.x * 256 + threadIdx.x;
    int n = blockIdx.y;
    if (col >= KCAT) return;
    float v = 0.f;
    if (col < E)          v = w_ih[(size_t)n * E + col];
    else if (col >= EPAD) v = w_hh[(size_t)n * H + (col - EPAD)];
    u16 hi = f2bf(v);
    dh[(size_t)n * KCAT + col] = hi;
    dl[(size_t)n * KCAT + col] = f2bf(v - bf2f(hi));
}

__global__ __launch_bounds__(256)
void tsplit_kernel(const float* __restrict__ src, u16* __restrict__ dh, u16* __restrict__ dl)
{
    int k = blockIdx.x * 256 + threadIdx.x;
    int n = blockIdx.y;
    float v = src[(size_t)k * H + n];
    u16 hi = f2bf(v);
    dh[(size_t)n * H + k] = hi;
    dl[(size_t)n * H + k] = f2bf(v - bf2f(hi));
}

__global__ __launch_bounds__(256)
void wrt_split_kernel(const float* __restrict__ wr, const float* __restrict__ wt,
                      u16* __restrict__ dh, u16* __restrict__ dl)
{
    int k = blockIdx.x * 256 + threadIdx.x;    // 0..H-1
    int n = blockIdx.y;                        // 0..2047
    float v = (n < H) ? wr[(size_t)k * H + n] : wt[(size_t)k * H + (n - H)];
    u16 hi = f2bf(v);
    dh[(size_t)n * H + k] = hi;
    dl[(size_t)n * H + k] = f2bf(v - bf2f(hi));
}

// ---------------------------------------------------------------------------
// Persistent LSTM scan. 256 blocks x 256 thr. Block (bx=k-tile of 16 units,
// by=32 rows); wave g owns gate g (weights resident). h is packed u32
// (hi|lo), exchanged via coherence point, staged once/block/step into LDS.
// ---------------------------------------------------------------------------
template<int PREMISE>
__global__ __launch_bounds__(256, 1)
void lstm_scan(const int* __restrict__ toks, int S,
               const float* __restrict__ emb,
               const u16* __restrict__ Wh, const u16* __restrict__ Wl,
               const float* __restrict__ b_ih, const float* __restrict__ b_hh,
               u32* __restrict__ hpk0, u32* __restrict__ hpk1,
               float* __restrict__ c, float* __restrict__ hmask,
               float* __restrict__ cmask,
               u16* __restrict__ seq_hi, u16* __restrict__ seq_lo,
               int* __restrict__ flags)
{
    const int tid  = threadIdx.x;
    const int lane = tid & 63;
    const int g    = tid >> 6;           // gate = wave
    const int l15  = lane & 15;
    const int lk8  = (lane >> 4) * 8;
    const int bx   = blockIdx.x & 63;
    const int by   = blockIdx.x >> 6;    // 0..3
    const int k0   = bx * 16;
    const int m0   = by * 32;

    // resident weights: rows n = g*H + k0 + l15, cols ks*32 + lk8
    bf16x8 wh_r[42], wl_r[42];
    {
        const u16* ph = Wh + (size_t)(g * H + k0 + l15) * KCAT + lk8;
        const u16* pl = Wl + (size_t)(g * H + k0 + l15) * KCAT + lk8;
#pragma unroll
        for (int ks = 0; ks < 42; ++ks) {
            wh_r[ks] = *(const bf16x8*)(ph + ks * 32);
            wl_r[ks] = *(const bf16x8*)(pl + ks * 32);
        }
    }
    const int ke = k0 + (tid & 15);
    const float bs0 = b_ih[0 * H + ke] + b_hh[0 * H + ke];
    const float bs1 = b_ih[1 * H + ke] + b_hh[1 * H + ke];
    const float bs2 = b_ih[2 * H + ke] + b_hh[2 * H + ke];
    const float bs3 = b_ih[3 * H + ke] + b_hh[3 * H + ke];

    __shared__ u16 hiL[32][1032];        // 66 KB (pad 1032: 16B-aligned rows)
    __shared__ u16 loL[32][1032];        // 66 KB
    __shared__ float gt[4][32][17];      // 8.7 KB

    for (int t = 0; t < S; ++t) {
        const u32* hin = (t & 1) ? hpk1 : hpk0;
        u32*      hout = (t & 1) ? hpk0 : hpk1;

        const float* ea[2];
#pragma unroll
        for (int mt = 0; mt < 2; ++mt) {
            int row = m0 + mt * 16 + l15;
            int tok = toks[row * S + t];
            ea[mt] = emb + (size_t)tok * E + lk8;
        }

        f32x4 acc[2] = {{0.f,0.f,0.f,0.f},{0.f,0.f,0.f,0.f}};

        // ---- emb segment (independent of previous h) ----
#pragma unroll
        for (int ks = 0; ks < 9; ++ks) {
#pragma unroll
            for (int mt = 0; mt < 2; ++mt) {
                float4 f0 = *(const float4*)(ea[mt] + ks * 32);
                float4 f1 = *(const float4*)(ea[mt] + ks * 32 + 4);
                float v[8] = {f0.x, f0.y, f0.z, f0.w, f1.x, f1.y, f1.z, f1.w};
                bf16x8 a_hi, a_lo;
#pragma unroll
                for (int j = 0; j < 8; ++j) {
                    u16 hi = f2bf(v[j]);
                    a_hi[j] = (short)hi;
                    a_lo[j] = (short)f2bf(v[j] - bf2f(hi));
                }
                acc[mt] = mfma16(a_hi, wh_r[ks], acc[mt]);
                acc[mt] = mfma16(a_lo, wh_r[ks], acc[mt]);
                acc[mt] = mfma16(a_hi, wl_r[ks], acc[mt]);
            }
        }
        {   // ks = 9: cols 288 + lk8 + j, guard k < E (weight pad cols are 0)
#pragma unroll
            for (int mt = 0; mt < 2; ++mt) {
                float v[8];
#pragma unroll
                for (int j = 0; j < 8; ++j) {
                    int k = 288 + lk8 + j;
                    v[j] = (k < E) ? ea[mt][k - lk8] : 0.f;
                }
                bf16x8 a_hi, a_lo;
#pragma unroll
                for (int j = 0; j < 8; ++j) {
                    u16 hi = f2bf(v[j]);
                    a_hi[j] = (short)hi;
                    a_lo[j] = (short)f2bf(v[j] - bf2f(hi));
                }
                acc[mt] = mfma16(a_hi, wh_r[9], acc[mt]);
                acc[mt] = mfma16(a_lo, wh_r[9], acc[mt]);
                acc[mt] = mfma16(a_hi, wl_r[9], acc[mt]);
            }
        }

        // ---- wait for previous step's h (emb work overlapped above) ----
        if (t > 0) flag_wait(flags, NB_L, t);

        // ---- cooperative stage: hin rows m0..m0+31 -> LDS (unpacked) ----
        {
            const u64* hsrc = (const u64*)(hin + (size_t)m0 * H);
#pragma unroll 16
            for (int j = 0; j < 64; ++j) {
                int i = j * 256 + tid;
                u64 v = aLd64(&hsrc[i]);
                u32 p0 = (u32)v, p1 = (u32)(v >> 32);
                int row = i >> 9, cp = (i & 511) * 2;
                *(u32*)&hiL[row][cp] = (p0 >> 16) | (p1 & 0xffff0000u);
                *(u32*)&loL[row][cp] = (p0 & 0xffffu) | (p1 << 16);
            }
        }
        __syncthreads();

        // ---- h segment from LDS ----
#pragma unroll
        for (int ks = 0; ks < 32; ++ks) {
#pragma unroll
            for (int mt = 0; mt < 2; ++mt) {
                bf16x8 a_hi = *(const bf16x8*)&hiL[mt * 16 + l15][ks * 32 + lk8];
                bf16x8 a_lo = *(const bf16x8*)&loL[mt * 16 + l15][ks * 32 + lk8];
                acc[mt] = mfma16(a_hi, wh_r[10 + ks], acc[mt]);
                acc[mt] = mfma16(a_lo, wh_r[10 + ks], acc[mt]);
                acc[mt] = mfma16(a_hi, wl_r[10 + ks], acc[mt]);
            }
        }
        __syncthreads();                 // hiL/loL reads done (reused next t)

        // ---- gate exchange via LDS ----
#pragma unroll
        for (int mt = 0; mt < 2; ++mt)
#pragma unroll
            for (int j = 0; j < 4; ++j)
                gt[g][mt * 16 + (lane >> 4) * 4 + j][l15] = acc[mt][j];
        __syncthreads();

        // ---- cell epilogue: 2 (m, ke) elements per thread ----
#pragma unroll
        for (int i = 0; i < 2; ++i) {
            int ml = (tid >> 4) + i * 16;        // 0..31
            int m  = m0 + ml;
            size_t idx = (size_t)m * H + ke;
            float gi = gt[0][ml][tid & 15] + bs0;
            float gf = gt[1][ml][tid & 15] + bs1;
            float gg = gt[2][ml][tid & 15] + bs2;
            float go = gt[3][ml][tid & 15] + bs3;
            float c2 = sigf(gf) * c[idx] + sigf(gi) * tanh_fast(gg);
            float h2 = sigf(go) * tanh_fast(c2);
            c[idx] = c2;                          // block-private
            aSt32(&hout[idx], packhl(h2));        // shared -> coherence point
            float mk = (toks[m * S + t] != 0) ? 1.f : 0.f;
            float hmv = mk * h2 + (1.f - mk) * hmask[idx];
            hmask[idx] = hmv;                     // block-private
            u16 mh = f2bf(hmv);
            u16 mlv = f2bf(hmv - bf2f(mh));
            if (PREMISE) {
                float cmv = mk * c2 + (1.f - mk) * cmask[idx];
                cmask[idx] = cmv;
                size_t yi = ((size_t)m * SP + t) * H + ke;   // Y [B][SP][H]
                seq_hi[yi] = mh; seq_lo[yi] = mlv;
            } else {
                size_t oi = ((size_t)t * B + m) * H + ke;    // outh [SH][B][H]
                seq_hi[oi] = mh; seq_lo[oi] = mlv;
            }
        }
        if (t + 1 < S) flag_arrive(flags, t + 1);
    }
}

// ---------------------------------------------------------------------------
// Persistent attention scan. 128 blocks x 256 thr; block = batch row b.
// Shared state (srt, packed r) via coherence-point atomics; r slab staged
// to LDS for phase A. 2 flag barriers per t.
// ---------------------------------------------------------------------------
__global__ __launch_bounds__(256, 1)
void attn_scan(const u16* __restrict__ firstH, const u16* __restrict__ firstL, // [B*SP][H]
               const u16* __restrict__ hsecH, const u16* __restrict__ hsecL,   // [SH*B][H]
               const u16* __restrict__ Wrth, const u16* __restrict__ Wrtl,     // [2048][1024]
               const u16* __restrict__ Yh, const u16* __restrict__ Yl,         // [B*SP][H]
               const float* __restrict__ wv,
               const int* __restrict__ ptoks, const int* __restrict__ htoks,
               float* __restrict__ srt,           // [B][2048] (secr | rwt)
               u32* __restrict__ rpk,             // [B][H] packed r
               float* __restrict__ r,             // [B][H] fp32 (block-private)
               int* __restrict__ flags)
{
    const int tid  = threadIdx.x;
    const int lane = tid & 63;
    const int w    = tid >> 6;
    const int l15  = lane & 15;
    const int lk8  = (lane >> 4) * 8;
    const int b    = blockIdx.x;

    __shared__ u16 rs_hi[16][1032];      // 33 KB
    __shared__ u16 rs_lo[16][1032];      // 33 KB
    __shared__ float sArr[SP];
    __shared__ float al[SP];
    __shared__ float red[SP];

    float wv_e[16];
#pragma unroll
    for (int e = 0; e < 16; ++e) wv_e[e] = wv[lane + e * 64];

    // phase-A tiling: all 4 waves of a block share pm0; n0 per wave
    const int pm0 = (blockIdx.x >> 4) * 16;                 // 16 batch rows
    const int n0  = (((blockIdx.x & 15) << 2) + w) * 32;    // 2 adjacent n-tiles

    for (int t = 0; t < SH; ++t) {
        // ---- stage rpk[pm0..pm0+15] -> LDS (unpacked) ----
        {
            const u64* rsrc = (const u64*)(rpk + (size_t)pm0 * H);
#pragma unroll 16
            for (int j = 0; j < 32; ++j) {
                int i = j * 256 + tid;
                u64 v = aLd64(&rsrc[i]);
                u32 p0 = (u32)v, p1 = (u32)(v >> 32);
                int row = i >> 9, cp = (i & 511) * 2;
                *(u32*)&rs_hi[row][cp] = (p0 >> 16) | (p1 & 0xffff0000u);
                *(u32*)&rs_lo[row][cp] = (p0 & 0xffffu) | (p1 << 16);
            }
        }
        __syncthreads();

        // ---- phase A: srt[m][n] for n in {n0, n0+16} ----
        {
            const u16* bp0 = Wrth + (size_t)(n0 + l15) * H + lk8;
            const u16* bp1 = Wrth + (size_t)(n0 + 16 + l15) * H + lk8;
            const ptrdiff_t dB = Wrtl - Wrth;
            f32x4 a0 = {0.f,0.f,0.f,0.f}, a1 = {0.f,0.f,0.f,0.f};
#pragma unroll 4
            for (int ks = 0; ks < 32; ++ks) {
                bf16x8 ahi = *(const bf16x8*)&rs_hi[l15][ks * 32 + lk8];
                bf16x8 alo = *(const bf16x8*)&rs_lo[l15][ks * 32 + lk8];
                bf16x8 b0h = *(const bf16x8*)(bp0 + ks * 32);
                bf16x8 b0l = *(const bf16x8*)(bp0 + dB + ks * 32);
                a0 = mfma16(ahi, b0h, a0);
                a0 = mfma16(alo, b0h, a0);
                a0 = mfma16(ahi, b0l, a0);
                bf16x8 b1h = *(const bf16x8*)(bp1 + ks * 32);
                bf16x8 b1l = *(const bf16x8*)(bp1 + dB + ks * 32);
                a1 = mfma16(ahi, b1h, a1);
                a1 = mfma16(alo, b1h, a1);
                a1 = mfma16(ahi, b1l, a1);
            }
#pragma unroll
            for (int j = 0; j < 4; ++j) {
                int mrow = pm0 + (lane >> 4) * 4 + j;
                aStF(&srt[(size_t)mrow * 2048 + n0 + l15],      a0[j]);
                aStF(&srt[(size_t)mrow * 2048 + n0 + 16 + l15], a1[j]);
            }
        }
        __syncthreads();                 // rs_* reads done before next stage
        flag_arrive(flags, 2 * t + 1);
        flag_wait(flags, NB_A, 2 * t + 1);

        // ---- phase B: scores for own b; s stays in LDS ----
        {
            float hsum[16];
            const u16* hbh = hsecH + ((size_t)t * B + b) * H;
            const u16* hbl = hsecL + ((size_t)t * B + b) * H;
            const float* sb = srt + (size_t)b * 2048;
#pragma unroll
            for (int e = 0; e < 16; ++e) {
                int hh = lane + e * 64;
                hsum[e] = bf2f(hbh[hh]) + bf2f(hbl[hh]) + aLdF(&sb[hh]);
            }
            for (int pp = 0; pp < 32; ++pp) {
                int p = w * 32 + pp;
                const u16* fph = firstH + ((size_t)b * SP + p) * H;
                const u16* fpl = firstL + ((size_t)b * SP + p) * H;
                float acc = 0.f;
#pragma unroll
                for (int e = 0; e < 16; ++e) {
                    int hh = lane + e * 64;
                    acc += tanh_fast(bf2f(fph[hh]) + bf2f(fpl[hh]) + hsum[e]) * wv_e[e];
                }
#pragma unroll
                for (int off = 32; off; off >>= 1) acc += __shfl_xor(acc, off);
                if (lane == 0)
                    sArr[p] = acc + ((ptoks[b * SP + p] != 0) ? 0.f : -1000.f);
            }
        }
        __syncthreads();

        // ---- phase C: softmax + r_t = alpha@Y + tanh(rwt); masked carry ----
        {
            if (tid < SP) { float v = sArr[tid]; al[tid] = v; red[tid] = v; }
            __syncthreads();
            for (int off = 64; off; off >>= 1) {
                if (tid < off) red[tid] = fmaxf(red[tid], red[tid + off]);
                __syncthreads();
            }
            float mx = red[0];
            __syncthreads();
            if (tid < SP) { float e = __expf(al[tid] - mx); al[tid] = e; red[tid] = e; }
            __syncthreads();
            for (int off = 64; off; off >>= 1) {
                if (tid < off) red[tid] += red[tid + off];
                __syncthreads();
            }
            float inv = 1.f / red[0];
            __syncthreads();
            if (tid < SP) al[tid] *= inv;
            __syncthreads();

            const int h0 = tid * 4;
            float a0 = 0.f, a1 = 0.f, a2 = 0.f, a3 = 0.f;
            const u16* yhp = Yh + (size_t)b * SP * H + h0;
            const u16* ylp = Yl + (size_t)b * SP * H + h0;
#pragma unroll 2
            for (int p = 0; p < SP; ++p) {
                float a = al[p];
                uint2 vh = *(const uint2*)(yhp + (size_t)p * H);
                uint2 vl = *(const uint2*)(ylp + (size_t)p * H);
                a0 += a * (__uint_as_float(vh.x << 16) + __uint_as_float(vl.x << 16));
                a1 += a * (__uint_as_float(vh.x & 0xffff0000u) + __uint_as_float(vl.x & 0xffff0000u));
                a2 += a * (__uint_as_float(vh.y << 16) + __uint_as_float(vl.y << 16));
                a3 += a * (__uint_as_float(vh.y & 0xffff0000u) + __uint_as_float(vl.y & 0xffff0000u));
            }
            float mk = (htoks[b * SH + t] != 0) ? 1.f : 0.f;
            const float* rwt = srt + (size_t)b * 2048 + H;
            float4 ro = *(const float4*)(r + (size_t)b * H + h0);
            float rn0 = a0 + tanh_fast(aLdF(&rwt[h0 + 0]));
            float rn1 = a1 + tanh_fast(aLdF(&rwt[h0 + 1]));
            float rn2 = a2 + tanh_fast(aLdF(&rwt[h0 + 2]));
            float rn3 = a3 + tanh_fast(aLdF(&rwt[h0 + 3]));
            float4 rv;
            rv.x = mk * rn0 + (1.f - mk) * ro.x;
            rv.y = mk * rn1 + (1.f - mk) * ro.y;
            rv.z = mk * rn2 + (1.f - mk) * ro.z;
            rv.w = mk * rn3 + (1.f - mk) * ro.w;
            *(float4*)(r + (size_t)b * H + h0) = rv;      // block-private
            u32 pk0 = packhl(rv.x), pk1 = packhl(rv.y);
            u32 pk2 = packhl(rv.z), pk3 = packhl(rv.w);
            u64* rp = (u64*)(rpk + (size_t)b * H + h0);
            aSt64(&rp[0], ((u64)pk1 << 32) | pk0);
            aSt64(&rp[1], ((u64)pk3 << 32) | pk2);
        }
        if (t + 1 < SH) {
            flag_arrive(flags, 2 * t + 2);
            flag_wait(flags, NB_A, 2 * t + 2);
        }
    }
}

// ---------------------------------------------------------------------------
// Split-bf16 MFMA GEMM: C = A[M,K] @ B^T, B stored [N][K] hi/lo.
// ---------------------------------------------------------------------------
template<bool SPLITOUT>
__global__ __launch_bounds__(256)
void gemm_mfma_kernel(const u16* __restrict__ Ah, const u16* __restrict__ Al,
                      const u16* __restrict__ Bh, const u16* __restrict__ Bl,
                      float* __restrict__ C, u16* __restrict__ Ch, u16* __restrict__ Cl,
                      int M, int N, int K)
{
    const int tid  = threadIdx.x;
    const int lane = tid & 63;
    const int wave = tid >> 6;
    const int l15  = lane & 15;
    const int lk8  = (lane >> 4) * 8;
    const int m0   = blockIdx.y * 64 + wave * 16;
    const int n0   = blockIdx.x * 64;

    const u16* ahp = Ah + (size_t)(m0 + l15) * K + lk8;
    const u16* alp = Al + (size_t)(m0 + l15) * K + lk8;
    const u16* bhp[4]; const u16* blp[4];
#pragma unroll
    for (int nt = 0; nt < 4; ++nt) {
        size_t o = (size_t)(n0 + nt * 16 + l15) * K + lk8;
        bhp[nt] = Bh + o; blp[nt] = Bl + o;
    }
    f32x4 acc[4] = {{0.f,0.f,0.f,0.f},{0.f,0.f,0.f,0.f},
                    {0.f,0.f,0.f,0.f},{0.f,0.f,0.f,0.f}};
    const int nks = K >> 5;
#pragma unroll 2
    for (int ks = 0; ks < nks; ++ks) {
        bf16x8 a_hi = *(const bf16x8*)(ahp + ks * 32);
        bf16x8 a_lo = *(const bf16x8*)(alp + ks * 32);
#pragma unroll
        for (int nt = 0; nt < 4; ++nt) {
            bf16x8 b_hi = *(const bf16x8*)(bhp[nt] + ks * 32);
            bf16x8 b_lo = *(const bf16x8*)(blp[nt] + ks * 32);
            acc[nt] = mfma16(a_hi, b_hi, acc[nt]);
            acc[nt] = mfma16(a_lo, b_hi, acc[nt]);
            acc[nt] = mfma16(a_hi, b_lo, acc[nt]);
        }
    }
#pragma unroll
    for (int nt = 0; nt < 4; ++nt)
#pragma unroll
        for (int j = 0; j < 4; ++j) {
            int m = m0 + (lane >> 4) * 4 + j;
            size_t idx = (size_t)m * N + n0 + nt * 16 + l15;
            if (SPLITOUT) {
                float v = acc[nt][j];
                u16 hi = f2bf(v);
                Ch[idx] = hi;
                Cl[idx] = f2bf(v - bf2f(hi));
            } else {
                C[idx] = acc[nt][j];
            }
        }
}

// ---------------------------------------------------------------------------
// Skinny fp32 GEMM (M=128): tile 32x64, BK=16, 256 thr, dbuf (verified).
// ---------------------------------------------------------------------------
template<bool ACC>
__global__ __launch_bounds__(256)
void skinny_kernel(const float* __restrict__ A,
                   const float* __restrict__ B1, float* __restrict__ C1,
                   const float* __restrict__ B2, float* __restrict__ C2,
                   int K, int N, int ntiles)
{
    const int tid = threadIdx.x;
    const int tx = tid & 15, ty = tid >> 4;
    const int bx = blockIdx.x;
    const float* Bw = (bx < ntiles) ? B1 : B2;
    float* C       = (bx < ntiles) ? C1 : C2;
    const int n0 = ((bx < ntiles) ? bx : bx - ntiles) * 64;
    const int m0 = blockIdx.y * 32;

    __shared__ float As[2][16][34];
    __shared__ float Bs[2][16][68];
    const int sq = tid & 15, sm = tid >> 4;
    const int nb = tid & 63, kb = tid >> 6;

    float ra[2], rb[4];
    auto ldA = [&](int k0, int rr) -> float {
        return A[(size_t)(m0 + sm + 16 * rr) * K + k0 + sq];
    };
    auto ldB = [&](int k0, int rr) -> float {
        return Bw[(size_t)(k0 + kb + 4 * rr) * N + n0 + nb];
    };

    float acc[2][4] = {};
    ra[0] = ldA(0, 0); ra[1] = ldA(0, 1);
#pragma unroll
    for (int rr = 0; rr < 4; ++rr) rb[rr] = ldB(0, rr);
    As[0][sq][sm] = ra[0]; As[0][sq][sm + 16] = ra[1];
#pragma unroll
    for (int rr = 0; rr < 4; ++rr) Bs[0][kb + 4 * rr][nb] = rb[rr];
    __syncthreads();

    const int NKT = K / 16;
    for (int kt = 0; kt < NKT; ++kt) {
        const int buf = kt & 1;
        if (kt + 1 < NKT) {
            int k0 = (kt + 1) * 16;
            ra[0] = ldA(k0, 0); ra[1] = ldA(k0, 1);
#pragma unroll
            for (int rr = 0; rr < 4; ++rr) rb[rr] = ldB(k0, rr);
        }
#pragma unroll
        for (int qq = 0; qq < 16; ++qq) {
            float2 a2 = *(const float2*)&As[buf][qq][ty * 2];
            float4 b4 = *(const float4*)&Bs[buf][qq][tx * 4];
            acc[0][0] += a2.x * b4.x; acc[0][1] += a2.x * b4.y;
            acc[0][2] += a2.x * b4.z; acc[0][3] += a2.x * b4.w;
            acc[1][0] += a2.y * b4.x; acc[1][1] += a2.y * b4.y;
            acc[1][2] += a2.y * b4.z; acc[1][3] += a2.y * b4.w;
        }
        if (kt + 1 < NKT) {
            const int nbuf = buf ^ 1;
            As[nbuf][sq][sm] = ra[0]; As[nbuf][sq][sm + 16] = ra[1];
#pragma unroll
            for (int rr = 0; rr < 4; ++rr) Bs[nbuf][kb + 4 * rr][nb] = rb[rr];
            __syncthreads();
        }
    }
#pragma unroll
    for (int i = 0; i < 2; ++i) {
        int m = m0 + ty * 2 + i;
        float* cp = &C[(size_t)m * N + n0 + tx * 4];
        float4 v = make_float4(acc[i][0], acc[i][1], acc[i][2], acc[i][3]);
        if (ACC) {
            float4 o = *(const float4*)cp;
            v.x += o.x; v.y += o.y; v.z += o.z; v.w += o.w;
        }
        *(float4*)cp = v;
    }
}

// logits -> softmax over 4 classes
__global__ __launch_bounds__(256)
void final_kernel(const float* __restrict__ pre,
                  const float* __restrict__ fc_w,
                  const float* __restrict__ fc_b,
                  float* __restrict__ out)
{
    int b = blockIdx.x;
    float acc[NC] = {0.f, 0.f, 0.f, 0.f};
    for (int k = threadIdx.x; k < H; k += 256) {
        float hs = tanh_fast(pre[(size_t)b * H + k]);
#pragma unroll
        for (int cc = 0; cc < NC; ++cc) acc[cc] += hs * fc_w[cc * H + k];
    }
    __shared__ float red[NC][256];
#pragma unroll
    for (int cc = 0; cc < NC; ++cc) red[cc][threadIdx.x] = acc[cc];
    __syncthreads();
    for (int off = 128; off > 0; off >>= 1) {
        if (threadIdx.x < off)
#pragma unroll
            for (int cc = 0; cc < NC; ++cc)
                red[cc][threadIdx.x] += red[cc][threadIdx.x + off];
        __syncthreads();
    }
    if (threadIdx.x == 0) {
        float l[NC], mx = -1e30f;
#pragma unroll
        for (int cc = 0; cc < NC; ++cc) { l[cc] = red[cc][0] + fc_b[cc]; mx = fmaxf(mx, l[cc]); }
        float sum = 0.f;
#pragma unroll
        for (int cc = 0; cc < NC; ++cc) { l[cc] = __expf(l[cc] - mx); sum += l[cc]; }
#pragma unroll
        for (int cc = 0; cc < NC; ++cc) out[b * NC + cc] = l[cc] / sum;
    }
}

extern "C" void kernel_launch(void* const* d_in, const int* in_sizes, int n_in,
                              void* d_out, int out_size, void* d_ws, size_t ws_size,
                              hipStream_t stream)
{
    const int*   prem   = (const int*)d_in[0];
    const int*   hyp    = (const int*)d_in[1];
    const float* emb    = (const float*)d_in[2];
    const float* w_ih_p = (const float*)d_in[3];
    const float* w_hh_p = (const float*)d_in[4];
    const float* b_ih_p = (const float*)d_in[5];
    const float* b_hh_p = (const float*)d_in[6];
    const float* w_ih_h = (const float*)d_in[7];
    const float* w_hh_h = (const float*)d_in[8];
    const float* b_ih_h = (const float*)d_in[9];
    const float* b_hh_h = (const float*)d_in[10];
    const float* wy     = (const float*)d_in[11];
    const float* wh     = (const float*)d_in[12];
    const float* wr     = (const float*)d_in[13];
    const float* wv     = (const float*)d_in[14];
    const float* wt     = (const float*)d_in[15];
    const float* wp     = (const float*)d_in[16];
    const float* wx     = (const float*)d_in[17];
    const float* fc_w   = (const float*)d_in[18];
    const float* fc_b   = (const float*)d_in[19];
    float* out = (float*)d_out;
    (void)in_sizes; (void)n_in; (void)out_size; (void)ws_size;

    char* wsc = (char*)d_ws;
    size_t off = 0;
    auto alloc = [&](size_t bytes) -> void* {
        void* p = wsc + off;
        off += (bytes + 255) & ~(size_t)255;
        return p;
    };
    // split weight packs (~44 MB)
    u16* Wp_hi  = (u16*)alloc((size_t)G4H * KCAT * 2);
    u16* Wp_lo  = (u16*)alloc((size_t)G4H * KCAT * 2);
    u16* Wq_hi  = (u16*)alloc((size_t)G4H * KCAT * 2);
    u16* Wq_lo  = (u16*)alloc((size_t)G4H * KCAT * 2);
    u16* wyT_hi = (u16*)alloc((size_t)H * H * 2);
    u16* wyT_lo = (u16*)alloc((size_t)H * H * 2);
    u16* whT_hi = (u16*)alloc((size_t)H * H * 2);
    u16* whT_lo = (u16*)alloc((size_t)H * H * 2);
    u16* WrtH   = (u16*)alloc((size_t)2 * H * H * 2);
    u16* WrtL   = (u16*)alloc((size_t)2 * H * H * 2);
    // sequence outputs + hoisted GEMM outputs, split bf16 (~151 MB)
    u16* Y_hi   = (u16*)alloc((size_t)B * SP * H * 2);
    u16* Y_lo   = (u16*)alloc((size_t)B * SP * H * 2);
    u16* OH_hi  = (u16*)alloc((size_t)SH * B * H * 2);
    u16* OH_lo  = (u16*)alloc((size_t)SH * B * H * 2);
    u16* firstH = (u16*)alloc((size_t)B * SP * H * 2);
    u16* firstL = (u16*)alloc((size_t)B * SP * H * 2);
    u16* hsecH  = (u16*)alloc((size_t)SH * B * H * 2);
    u16* hsecL  = (u16*)alloc((size_t)SH * B * H * 2);
    const size_t BH = (size_t)B * H;
    // packed h ping-pong (contiguous for one memset)
    u32* hpk0 = (u32*)alloc(BH * 4);
    u32* hpk1 = (u32*)alloc(BH * 4);
    // c, hm, cm contiguous for one memset
    float* cbuf = (float*)alloc(BH * 4);
    float* hm   = (float*)alloc(BH * 4);
    float* cm   = (float*)alloc(BH * 4);
    float* r    = (float*)alloc(BH * 4);
    u32*   rpk  = (u32*)alloc(BH * 4);
    float* srt  = (float*)alloc((size_t)B * 2048 * 4);
    float* pre  = (float*)alloc(BH * 4);
    int*   bars = (int*)alloc(3 * 256 * sizeof(int));
    int* barP = bars; int* barH = bars + 256; int* barA = bars + 512;

    // -------- one-time splits --------
    dim3 gW((KCAT + 255) / 256, G4H);
    wcat_split_kernel<<<gW, 256, 0, stream>>>(w_ih_p, w_hh_p, Wp_hi, Wp_lo);
    wcat_split_kernel<<<gW, 256, 0, stream>>>(w_ih_h, w_hh_h, Wq_hi, Wq_lo);
    tsplit_kernel<<<dim3(H / 256, H), 256, 0, stream>>>(wy, wyT_hi, wyT_lo);
    tsplit_kernel<<<dim3(H / 256, H), 256, 0, stream>>>(wh, whT_hi, whT_lo);
    wrt_split_kernel<<<dim3(H / 256, 2 * H), 256, 0, stream>>>(wr, wt, WrtH, WrtL);

    hipMemsetAsync(hpk0, 0, 2 * BH * 4, stream);  // hpk0, hpk1
    hipMemsetAsync(cbuf, 0, 3 * BH * 4, stream);  // c, hm, cm
    hipMemsetAsync(r, 0, 2 * BH * 4, stream);     // r, rpk
    hipMemsetAsync(bars, 0, 3 * 256 * sizeof(int), stream);

    // -------- premise LSTM (persistent) --------
    lstm_scan<1><<<NB_L, 256, 0, stream>>>(
        prem, SP, emb, Wp_hi, Wp_lo, b_ih_p, b_hh_p,
        hpk0, hpk1, cbuf, hm, cm, Y_hi, Y_lo, barP);

    // -------- hypothesis LSTM: h=0, c = cm --------
    hipMemsetAsync(hpk0, 0, 2 * BH * 4, stream);
    hipMemsetAsync(hm, 0, BH * 4, stream);
    lstm_scan<0><<<NB_L, 256, 0, stream>>>(
        hyp, SH, emb, Wq_hi, Wq_lo, b_ih_h, b_hh_h,
        hpk0, hpk1, cm, hm, (float*)nullptr, OH_hi, OH_lo, barH);
    // hm = out_h_last

    // -------- hoisted GEMMs (split-in, split-out) --------
    gemm_mfma_kernel<true><<<dim3(H / 64, (B * SP) / 64), 256, 0, stream>>>(
        Y_hi, Y_lo, wyT_hi, wyT_lo, nullptr, firstH, firstL, B * SP, H, H);
    gemm_mfma_kernel<true><<<dim3(H / 64, (SH * B) / 64), 256, 0, stream>>>(
        OH_hi, OH_lo, whT_hi, whT_lo, nullptr, hsecH, hsecL, SH * B, H, H);

    // -------- attention scan (persistent) --------
    attn_scan<<<NB_A, 256, 0, stream>>>(
        firstH, firstL, hsecH, hsecL, WrtH, WrtL, Y_hi, Y_lo, wv, prem, hyp,
        srt, rpk, r, barA);

    // -------- final projection + softmax --------
    skinny_kernel<false><<<dim3(16, 4), 256, 0, stream>>>(r,  wp, pre, nullptr, nullptr, H, H, 16);
    skinny_kernel<true ><<<dim3(16, 4), 256, 0, stream>>>(hm, wx, pre, nullptr, nullptr, H, H, 16);
    final_kernel<<<B, 256, 0, stream>>>(pre, fc_w, fc_b, out);
}

// Round 6
// 11065.644 us; speedup vs baseline: 2.4250x; 1.2577x over previous
//
#include <hip/hip_runtime.h>

// SNLI attention-LSTM, MI355X. Round 6: fresh-address history + cached
// consumer reads; attention on all 256 CUs.
//  - h/r exchanged via per-step history slots (hseq[t], rseq[t]): producer
//    writes through (agent-scope store), consumers use NORMAL cached loads —
//    each slot is written before first read within the launch; dispatch
//    acquire invalidates L2 across launches. L2 now serves the 64x-redundant
//    h reads (was 32 MB/step of L2-bypassing fabric traffic).
//  - attn_scan: 256 blocks (2 per b: score p-halves + Y h-halves), score
//    halves via coherent sglob + 3rd flag barrier; phase-C unroll 8.
//  - workspace aliasing: hseqP<->OH/first, hseqH<->hsec, rseq<->Wp/Wq (~223MB).

using u16 = unsigned short;
using u32 = unsigned int;
using u64 = unsigned long long;
typedef short bf16x8 __attribute__((ext_vector_type(8)));
typedef float f32x4 __attribute__((ext_vector_type(4)));

constexpr int B  = 128;
constexpr int SP = 128;
constexpr int SH = 64;
constexpr int H  = 1024;
constexpr int E  = 300;
constexpr int NC = 4;
constexpr int G4H  = 4 * H;          // 4096
constexpr int EPAD = 320;            // E padded to multiple of 32
constexpr int KCAT = EPAD + H;       // 1344
constexpr int NB_L = 256;            // lstm persistent blocks
constexpr int NB_A = 256;            // attn persistent blocks (2 per b)
constexpr size_t BHE = (size_t)B * H;   // elements in one h slab

__device__ __forceinline__ float sigf(float x) { return 1.0f / (1.0f + __expf(-x)); }
__device__ __forceinline__ float tanh_fast(float x) {
    float e = __expf(2.0f * x);
    return 1.0f - 2.0f / (e + 1.0f);
}
__device__ __forceinline__ u16 f2bf(float x) {           // round-to-nearest-even
    union { float f; unsigned u; } v; v.f = x;
    unsigned r = v.u + 0x7fffu + ((v.u >> 16) & 1u);
    return (u16)(r >> 16);
}
__device__ __forceinline__ float bf2f(u16 h) {
    union { unsigned u; float f; } v; v.u = ((unsigned)h) << 16;
    return v.f;
}
__device__ __forceinline__ f32x4 mfma16(bf16x8 a, bf16x8 b, f32x4 c) {
    return __builtin_amdgcn_mfma_f32_16x16x32_bf16(a, b, c, 0, 0, 0);
}
__device__ __forceinline__ u32 packhl(float v) {
    u16 hi = f2bf(v);
    u16 lo = f2bf(v - bf2f(hi));
    return ((u32)hi << 16) | lo;
}

// ---- coherence-point (agent scope, relaxed) accessors ----
__device__ __forceinline__ float aLdF(const float* p) {
    return __hip_atomic_load(p, __ATOMIC_RELAXED, __HIP_MEMORY_SCOPE_AGENT);
}
__device__ __forceinline__ void aStF(float* p, float v) {
    __hip_atomic_store(p, v, __ATOMIC_RELAXED, __HIP_MEMORY_SCOPE_AGENT);
}
__device__ __forceinline__ void aSt32(u32* p, u32 v) {
    __hip_atomic_store(p, v, __ATOMIC_RELAXED, __HIP_MEMORY_SCOPE_AGENT);
}
__device__ __forceinline__ void aSt64(u64* p, u64 v) {
    __hip_atomic_store(p, v, __ATOMIC_RELAXED, __HIP_MEMORY_SCOPE_AGENT);
}

// ---- all-to-all flag barrier ----
__device__ __forceinline__ void flag_arrive(int* flags, int epoch) {
    asm volatile("s_waitcnt vmcnt(0)" ::: "memory");   // this wave's stores done
    __syncthreads();                                   // all waves done
    if (threadIdx.x == 0)
        __hip_atomic_store(&flags[blockIdx.x], epoch,
                           __ATOMIC_RELAXED, __HIP_MEMORY_SCOPE_AGENT);
}
__device__ __forceinline__ void flag_wait(int* flags, int n, int epoch) {
    for (;;) {
        int v = (threadIdx.x < n)
            ? __hip_atomic_load(&flags[threadIdx.x], __ATOMIC_RELAXED,
                                __HIP_MEMORY_SCOPE_AGENT)
            : epoch;
        if (__syncthreads_and(v >= epoch)) break;
        __builtin_amdgcn_s_sleep(8);
    }
    asm volatile("" ::: "memory");       // compiler barrier: no load hoisting
    __builtin_amdgcn_sched_barrier(0);
}

// ---------------------------------------------------------------------------
// Prep kernels
// ---------------------------------------------------------------------------
__global__ __launch_bounds__(256)
void wcat_split_kernel(const float* __restrict__ w_ih, const float* __restrict__ w_hh,
                       u16* __restrict__ dh, u16* __restrict__ dl)
{
    int col = blockIdx.x * 256 + threadIdx.x;
    int n = blockIdx.y;
    if (col >= KCAT) return;
    float v = 0.f;
    if (col < E)          v = w_ih[(size_t)n * E + col];
    else if (col >= EPAD) v = w_hh[(size_t)n * H + (col - EPAD)];
    u16 hi = f2bf(v);
    dh[(size_t)n * KCAT + col] = hi;
    dl[(size_t)n * KCAT + col] = f2bf(v - bf2f(hi));
}

__global__ __launch_bounds__(256)
void tsplit_kernel(const float* __restrict__ src, u16* __restrict__ dh, u16* __restrict__ dl)
{
    int k = blockIdx.x * 256 + threadIdx.x;
    int n = blockIdx.y;
    float v = src[(size_t)k * H + n];
    u16 hi = f2bf(v);
    dh[(size_t)n * H + k] = hi;
    dl[(size_t)n * H + k] = f2bf(v - bf2f(hi));
}

__global__ __launch_bounds__(256)
void wrt_split_kernel(const float* __restrict__ wr, const float* __restrict__ wt,
                      u16* __restrict__ dh, u16* __restrict__ dl)
{
    int k = blockIdx.x * 256 + threadIdx.x;    // 0..H-1
    int n = blockIdx.y;                        // 0..2047
    float v = (n < H) ? wr[(size_t)k * H + n] : wt[(size_t)k * H + (n - H)];
    u16 hi = f2bf(v);
    dh[(size_t)n * H + k] = hi;
    dl[(size_t)n * H + k] = f2bf(v - bf2f(hi));
}

// ---------------------------------------------------------------------------
// Persistent LSTM scan. 256 blocks x 256 thr. h history hseq[t] (packed u32):
// written via coherence point, read via NORMAL cached loads (fresh address).
// ---------------------------------------------------------------------------
template<int PREMISE>
__global__ __launch_bounds__(256, 1)
void lstm_scan(const int* __restrict__ toks, int S,
               const float* __restrict__ emb,
               const u16* __restrict__ Wh, const u16* __restrict__ Wl,
               const float* __restrict__ b_ih, const float* __restrict__ b_hh,
               const u32* __restrict__ h0,    // zeros
               u32* __restrict__ hseq,        // [S][B][H] packed history
               float* __restrict__ c, float* __restrict__ hmask,
               float* __restrict__ cmask,
               u16* __restrict__ seq_hi, u16* __restrict__ seq_lo,
               int* __restrict__ flags)
{
    const int tid  = threadIdx.x;
    const int lane = tid & 63;
    const int g    = tid >> 6;           // gate = wave
    const int l15  = lane & 15;
    const int lk8  = (lane >> 4) * 8;
    const int bx   = blockIdx.x & 63;
    const int by   = blockIdx.x >> 6;    // 0..3
    const int k0   = bx * 16;
    const int m0   = by * 32;

    // resident weights: rows n = g*H + k0 + l15, cols ks*32 + lk8
    bf16x8 wh_r[42], wl_r[42];
    {
        const u16* ph = Wh + (size_t)(g * H + k0 + l15) * KCAT + lk8;
        const u16* pl = Wl + (size_t)(g * H + k0 + l15) * KCAT + lk8;
#pragma unroll
        for (int ks = 0; ks < 42; ++ks) {
            wh_r[ks] = *(const bf16x8*)(ph + ks * 32);
            wl_r[ks] = *(const bf16x8*)(pl + ks * 32);
        }
    }
    const int ke = k0 + (tid & 15);
    const float bs0 = b_ih[0 * H + ke] + b_hh[0 * H + ke];
    const float bs1 = b_ih[1 * H + ke] + b_hh[1 * H + ke];
    const float bs2 = b_ih[2 * H + ke] + b_hh[2 * H + ke];
    const float bs3 = b_ih[3 * H + ke] + b_hh[3 * H + ke];

    __shared__ u16 hiL[32][1032];        // 66 KB
    __shared__ u16 loL[32][1032];        // 66 KB
    __shared__ float gt[4][32][17];      // 8.7 KB

    for (int t = 0; t < S; ++t) {
        const u32* hin = (t == 0) ? h0 : (hseq + (size_t)(t - 1) * BHE);
        u32*      hout = hseq + (size_t)t * BHE;

        const float* ea[2];
#pragma unroll
        for (int mt = 0; mt < 2; ++mt) {
            int row = m0 + mt * 16 + l15;
            int tok = toks[row * S + t];
            ea[mt] = emb + (size_t)tok * E + lk8;
        }

        f32x4 acc[2] = {{0.f,0.f,0.f,0.f},{0.f,0.f,0.f,0.f}};

        // ---- emb segment (independent of previous h) ----
#pragma unroll
        for (int ks = 0; ks < 9; ++ks) {
#pragma unroll
            for (int mt = 0; mt < 2; ++mt) {
                float4 f0 = *(const float4*)(ea[mt] + ks * 32);
                float4 f1 = *(const float4*)(ea[mt] + ks * 32 + 4);
                float v[8] = {f0.x, f0.y, f0.z, f0.w, f1.x, f1.y, f1.z, f1.w};
                bf16x8 a_hi, a_lo;
#pragma unroll
                for (int j = 0; j < 8; ++j) {
                    u16 hi = f2bf(v[j]);
                    a_hi[j] = (short)hi;
                    a_lo[j] = (short)f2bf(v[j] - bf2f(hi));
                }
                acc[mt] = mfma16(a_hi, wh_r[ks], acc[mt]);
                acc[mt] = mfma16(a_lo, wh_r[ks], acc[mt]);
                acc[mt] = mfma16(a_hi, wl_r[ks], acc[mt]);
            }
        }
        {   // ks = 9: cols 288 + lk8 + j, guard k < E (weight pad cols are 0)
#pragma unroll
            for (int mt = 0; mt < 2; ++mt) {
                float v[8];
#pragma unroll
                for (int j = 0; j < 8; ++j) {
                    int k = 288 + lk8 + j;
                    v[j] = (k < E) ? ea[mt][k - lk8] : 0.f;
                }
                bf16x8 a_hi, a_lo;
#pragma unroll
                for (int j = 0; j < 8; ++j) {
                    u16 hi = f2bf(v[j]);
                    a_hi[j] = (short)hi;
                    a_lo[j] = (short)f2bf(v[j] - bf2f(hi));
                }
                acc[mt] = mfma16(a_hi, wh_r[9], acc[mt]);
                acc[mt] = mfma16(a_lo, wh_r[9], acc[mt]);
                acc[mt] = mfma16(a_hi, wl_r[9], acc[mt]);
            }
        }

        // ---- wait for previous step's h (emb work overlapped above) ----
        if (t > 0) flag_wait(flags, NB_L, t);

        // ---- cooperative stage: hin rows m0..m0+31 -> LDS (CACHED loads) ----
        {
            const u64* hsrc = (const u64*)(hin + (size_t)m0 * H);
#pragma unroll 16
            for (int j = 0; j < 64; ++j) {
                int i = j * 256 + tid;
                u64 v = hsrc[i];
                u32 p0 = (u32)v, p1 = (u32)(v >> 32);
                int row = i >> 9, cp = (i & 511) * 2;
                *(u32*)&hiL[row][cp] = (p0 >> 16) | (p1 & 0xffff0000u);
                *(u32*)&loL[row][cp] = (p0 & 0xffffu) | (p1 << 16);
            }
        }
        __syncthreads();

        // ---- h segment from LDS ----
#pragma unroll
        for (int ks = 0; ks < 32; ++ks) {
#pragma unroll
            for (int mt = 0; mt < 2; ++mt) {
                bf16x8 a_hi = *(const bf16x8*)&hiL[mt * 16 + l15][ks * 32 + lk8];
                bf16x8 a_lo = *(const bf16x8*)&loL[mt * 16 + l15][ks * 32 + lk8];
                acc[mt] = mfma16(a_hi, wh_r[10 + ks], acc[mt]);
                acc[mt] = mfma16(a_lo, wh_r[10 + ks], acc[mt]);
                acc[mt] = mfma16(a_hi, wl_r[10 + ks], acc[mt]);
            }
        }
        __syncthreads();                 // hiL/loL reads done (reused next t)

        // ---- gate exchange via LDS ----
#pragma unroll
        for (int mt = 0; mt < 2; ++mt)
#pragma unroll
            for (int j = 0; j < 4; ++j)
                gt[g][mt * 16 + (lane >> 4) * 4 + j][l15] = acc[mt][j];
        __syncthreads();

        // ---- cell epilogue ----
#pragma unroll
        for (int i = 0; i < 2; ++i) {
            int ml = (tid >> 4) + i * 16;        // 0..31
            int m  = m0 + ml;
            size_t idx = (size_t)m * H + ke;
            float gi = gt[0][ml][tid & 15] + bs0;
            float gf = gt[1][ml][tid & 15] + bs1;
            float gg = gt[2][ml][tid & 15] + bs2;
            float go = gt[3][ml][tid & 15] + bs3;
            float c2 = sigf(gf) * c[idx] + sigf(gi) * tanh_fast(gg);
            float h2 = sigf(go) * tanh_fast(c2);
            c[idx] = c2;                          // block-private
            aSt32(&hout[idx], packhl(h2));        // write-through (fresh slot)
            float mk = (toks[m * S + t] != 0) ? 1.f : 0.f;
            float hmv = mk * h2 + (1.f - mk) * hmask[idx];
            hmask[idx] = hmv;                     // block-private
            u16 mh = f2bf(hmv);
            u16 mlv = f2bf(hmv - bf2f(mh));
            if (PREMISE) {
                float cmv = mk * c2 + (1.f - mk) * cmask[idx];
                cmask[idx] = cmv;
                size_t yi = ((size_t)m * SP + t) * H + ke;   // Y [B][SP][H]
                seq_hi[yi] = mh; seq_lo[yi] = mlv;
            } else {
                size_t oi = ((size_t)t * B + m) * H + ke;    // outh [SH][B][H]
                seq_hi[oi] = mh; seq_lo[oi] = mlv;
            }
        }
        if (t + 1 < S) flag_arrive(flags, t + 1);
    }
}

// ---------------------------------------------------------------------------
// Persistent attention scan. 256 blocks x 256 thr; b = blockIdx>>1,
// sub = blockIdx&1 (p-half for scores, h-half for Y-reduce). r history
// rseq[t] (packed u32): coherent writes, cached reads. 3 flag barriers/t.
// ---------------------------------------------------------------------------
__global__ __launch_bounds__(256, 1)
void attn_scan(const u16* __restrict__ firstH, const u16* __restrict__ firstL, // [B*SP][H]
               const u16* __restrict__ hsecH, const u16* __restrict__ hsecL,   // [SH*B][H]
               const u16* __restrict__ Wrth, const u16* __restrict__ Wrtl,     // [2048][1024]
               const u16* __restrict__ Yh, const u16* __restrict__ Yl,         // [B*SP][H]
               const float* __restrict__ wv,
               const int* __restrict__ ptoks, const int* __restrict__ htoks,
               float* __restrict__ srt,           // [B][2048] coherent
               float* __restrict__ sglob,         // [B][SP] coherent scores
               u32* __restrict__ rseq,            // [SH+1][B][H] packed history
               float* __restrict__ r,             // [B][H] fp32 (half-owned)
               int* __restrict__ flags)
{
    const int tid  = threadIdx.x;
    const int lane = tid & 63;
    const int w    = tid >> 6;
    const int l15  = lane & 15;
    const int lk8  = (lane >> 4) * 8;
    const int b    = blockIdx.x >> 1;
    const int sub  = blockIdx.x & 1;

    __shared__ u16 rs_hi[16][1032];      // 33 KB
    __shared__ u16 rs_lo[16][1032];      // 33 KB
    __shared__ float al[SP];
    __shared__ float red[SP];

    float wv_e[16];
#pragma unroll
    for (int e = 0; e < 16; ++e) wv_e[e] = wv[lane + e * 64];

    // phase-A task: block stages one 16-row r slab; each wave one 16-col tile
    const int pm0 = (blockIdx.x >> 5) * 16;                   // 8 m-tiles
    const int n0  = (((blockIdx.x & 31) << 2) + w) * 16;      // 128 n-tiles
    const ptrdiff_t dB = Wrtl - Wrth;

    for (int t = 0; t < SH; ++t) {
        // ---- stage rseq[t] slab -> LDS (CACHED loads, fresh address) ----
        {
            const u64* rsrc = (const u64*)(rseq + (size_t)t * BHE + (size_t)pm0 * H);
#pragma unroll 16
            for (int j = 0; j < 32; ++j) {
                int i = j * 256 + tid;
                u64 v = rsrc[i];
                u32 p0 = (u32)v, p1 = (u32)(v >> 32);
                int row = i >> 9, cp = (i & 511) * 2;
                *(u32*)&rs_hi[row][cp] = (p0 >> 16) | (p1 & 0xffff0000u);
                *(u32*)&rs_lo[row][cp] = (p0 & 0xffffu) | (p1 << 16);
            }
        }
        __syncthreads();

        // ---- phase A: srt[pm0..+15][n0..+15] ----
        {
            const u16* bp0 = Wrth + (size_t)(n0 + l15) * H + lk8;
            f32x4 a0 = {0.f,0.f,0.f,0.f};
#pragma unroll 4
            for (int ks = 0; ks < 32; ++ks) {
                bf16x8 ahi = *(const bf16x8*)&rs_hi[l15][ks * 32 + lk8];
                bf16x8 alo = *(const bf16x8*)&rs_lo[l15][ks * 32 + lk8];
                bf16x8 b0h = *(const bf16x8*)(bp0 + ks * 32);
                bf16x8 b0l = *(const bf16x8*)(bp0 + dB + ks * 32);
                a0 = mfma16(ahi, b0h, a0);
                a0 = mfma16(alo, b0h, a0);
                a0 = mfma16(ahi, b0l, a0);
            }
#pragma unroll
            for (int j = 0; j < 4; ++j) {
                int mrow = pm0 + (lane >> 4) * 4 + j;
                aStF(&srt[(size_t)mrow * 2048 + n0 + l15], a0[j]);
            }
        }
        flag_arrive(flags, 3 * t + 1);
        flag_wait(flags, NB_A, 3 * t + 1);

        // ---- phase B: scores for own p-half; write coherent sglob ----
        {
            float hsum[16];
            const u16* hbh = hsecH + ((size_t)t * B + b) * H;
            const u16* hbl = hsecL + ((size_t)t * B + b) * H;
            const float* sb = srt + (size_t)b * 2048;
#pragma unroll
            for (int e = 0; e < 16; ++e) {
                int hh = lane + e * 64;
                hsum[e] = bf2f(hbh[hh]) + bf2f(hbl[hh]) + aLdF(&sb[hh]);
            }
            for (int pp = 0; pp < 16; ++pp) {
                int p = sub * 64 + w * 16 + pp;
                const u16* fph = firstH + ((size_t)b * SP + p) * H;
                const u16* fpl = firstL + ((size_t)b * SP + p) * H;
                float acc = 0.f;
#pragma unroll
                for (int e = 0; e < 16; ++e) {
                    int hh = lane + e * 64;
                    acc += tanh_fast(bf2f(fph[hh]) + bf2f(fpl[hh]) + hsum[e]) * wv_e[e];
                }
#pragma unroll
                for (int off = 32; off; off >>= 1) acc += __shfl_xor(acc, off);
                if (lane == 0)
                    aStF(&sglob[b * SP + p],
                         acc + ((ptoks[b * SP + p] != 0) ? 0.f : -1000.f));
            }
        }
        flag_arrive(flags, 3 * t + 2);
        flag_wait(flags, NB_A, 3 * t + 2);

        // ---- phase C: softmax + r update over own h-half ----
        {
            if (tid < SP) { float v = aLdF(&sglob[b * SP + tid]); al[tid] = v; red[tid] = v; }
            __syncthreads();
            for (int off = 64; off; off >>= 1) {
                if (tid < off) red[tid] = fmaxf(red[tid], red[tid + off]);
                __syncthreads();
            }
            float mx = red[0];
            __syncthreads();
            if (tid < SP) { float e = __expf(al[tid] - mx); al[tid] = e; red[tid] = e; }
            __syncthreads();
            for (int off = 64; off; off >>= 1) {
                if (tid < off) red[tid] += red[tid + off];
                __syncthreads();
            }
            float inv = 1.f / red[0];
            __syncthreads();
            if (tid < SP) al[tid] *= inv;
            __syncthreads();

            const int c0 = sub * 512 + tid * 2;    // 2 cols per thread
            const u16* ybh = Yh + (size_t)b * SP * H + c0;
            const u16* ybl = Yl + (size_t)b * SP * H + c0;
            float a0 = 0.f, a1 = 0.f, b0 = 0.f, b1 = 0.f;
#pragma unroll 8
            for (int p = 0; p < SP; ++p) {
                float a = al[p];
                u32 vh = *(const u32*)(ybh + (size_t)p * H);
                u32 vl = *(const u32*)(ybl + (size_t)p * H);
                float e0 = __uint_as_float(vh << 16) + __uint_as_float(vl << 16);
                float e1 = __uint_as_float(vh & 0xffff0000u) + __uint_as_float(vl & 0xffff0000u);
                if (p & 1) { b0 += a * e0; b1 += a * e1; }
                else       { a0 += a * e0; a1 += a * e1; }
            }
            a0 += b0; a1 += b1;
            float mk = (htoks[b * SH + t] != 0) ? 1.f : 0.f;
            float rwt0 = aLdF(&srt[(size_t)b * 2048 + H + c0]);
            float rwt1 = aLdF(&srt[(size_t)b * 2048 + H + c0 + 1]);
            float ro0 = r[(size_t)b * H + c0];
            float ro1 = r[(size_t)b * H + c0 + 1];
            float rn0 = a0 + tanh_fast(rwt0);
            float rn1 = a1 + tanh_fast(rwt1);
            float rv0 = mk * rn0 + (1.f - mk) * ro0;
            float rv1 = mk * rn1 + (1.f - mk) * ro1;
            r[(size_t)b * H + c0]     = rv0;       // block-private half
            r[(size_t)b * H + c0 + 1] = rv1;
            u32 pk0 = packhl(rv0), pk1 = packhl(rv1);
            aSt64((u64*)(rseq + (size_t)(t + 1) * BHE + (size_t)b * H + c0),
                  ((u64)pk1 << 32) | pk0);
        }
        if (t + 1 < SH) {
            flag_arrive(flags, 3 * t + 3);
            flag_wait(flags, NB_A, 3 * t + 3);
        }
    }
}

// ---------------------------------------------------------------------------
// Split-bf16 MFMA GEMM: C = A[M,K] @ B^T, B stored [N][K] hi/lo.
// ---------------------------------------------------------------------------
template<bool SPLITOUT>
__global__ __launch_bounds__(256)
void gemm_mfma_kernel(const u16* __restrict__ Ah, const u16* __restrict__ Al,
                      const u16* __restrict__ Bh, const u16* __restrict__ Bl,
                      float* __restrict__ C, u16* __restrict__ Ch, u16* __restrict__ Cl,
                      int M, int N, int K)
{
    const int tid  = threadIdx.x;
    const int lane = tid & 63;
    const int wave = tid >> 6;
    const int l15  = lane & 15;
    const int lk8  = (lane >> 4) * 8;
    const int m0   = blockIdx.y * 64 + wave * 16;
    const int n0   = blockIdx.x * 64;

    const u16* ahp = Ah + (size_t)(m0 + l15) * K + lk8;
    const u16* alp = Al + (size_t)(m0 + l15) * K + lk8;
    const u16* bhp[4]; const u16* blp[4];
#pragma unroll
    for (int nt = 0; nt < 4; ++nt) {
        size_t o = (size_t)(n0 + nt * 16 + l15) * K + lk8;
        bhp[nt] = Bh + o; blp[nt] = Bl + o;
    }
    f32x4 acc[4] = {{0.f,0.f,0.f,0.f},{0.f,0.f,0.f,0.f},
                    {0.f,0.f,0.f,0.f},{0.f,0.f,0.f,0.f}};
    const int nks = K >> 5;
#pragma unroll 2
    for (int ks = 0; ks < nks; ++ks) {
        bf16x8 a_hi = *(const bf16x8*)(ahp + ks * 32);
        bf16x8 a_lo = *(const bf16x8*)(alp + ks * 32);
#pragma unroll
        for (int nt = 0; nt < 4; ++nt) {
            bf16x8 b_hi = *(const bf16x8*)(bhp[nt] + ks * 32);
            bf16x8 b_lo = *(const bf16x8*)(blp[nt] + ks * 32);
            acc[nt] = mfma16(a_hi, b_hi, acc[nt]);
            acc[nt] = mfma16(a_lo, b_hi, acc[nt]);
            acc[nt] = mfma16(a_hi, b_lo, acc[nt]);
        }
    }
#pragma unroll
    for (int nt = 0; nt < 4; ++nt)
#pragma unroll
        for (int j = 0; j < 4; ++j) {
            int m = m0 + (lane >> 4) * 4 + j;
            size_t idx = (size_t)m * N + n0 + nt * 16 + l15;
            if (SPLITOUT) {
                float v = acc[nt][j];
                u16 hi = f2bf(v);
                Ch[idx] = hi;
                Cl[idx] = f2bf(v - bf2f(hi));
            } else {
                C[idx] = acc[nt][j];
            }
        }
}

// ---------------------------------------------------------------------------
// Skinny fp32 GEMM (M=128): tile 32x64, BK=16, 256 thr, dbuf (verified).
// ---------------------------------------------------------------------------
template<bool ACC>
__global__ __launch_bounds__(256)
void skinny_kernel(const float* __restrict__ A,
                   const float* __restrict__ B1, float* __restrict__ C1,
                   const float* __restrict__ B2, float* __restrict__ C2,
                   int K, int N, int ntiles)
{
    const int tid = threadIdx.x;
    const int tx = tid & 15, ty = tid >> 4;
    const int bx = blockIdx.x;
    const float* Bw = (bx < ntiles) ? B1 : B2;
    float* C       = (bx < ntiles) ? C1 : C2;
    const int n0 = ((bx < ntiles) ? bx : bx - ntiles) * 64;
    const int m0 = blockIdx.y * 32;

    __shared__ float As[2][16][34];
    __shared__ float Bs[2][16][68];
    const int sq = tid & 15, sm = tid >> 4;
    const int nb = tid & 63, kb = tid >> 6;

    float ra[2], rb[4];
    auto ldA = [&](int k0, int rr) -> float {
        return A[(size_t)(m0 + sm + 16 * rr) * K + k0 + sq];
    };
    auto ldB = [&](int k0, int rr) -> float {
        return Bw[(size_t)(k0 + kb + 4 * rr) * N + n0 + nb];
    };

    float acc[2][4] = {};
    ra[0] = ldA(0, 0); ra[1] = ldA(0, 1);
#pragma unroll
    for (int rr = 0; rr < 4; ++rr) rb[rr] = ldB(0, rr);
    As[0][sq][sm] = ra[0]; As[0][sq][sm + 16] = ra[1];
#pragma unroll
    for (int rr = 0; rr < 4; ++rr) Bs[0][kb + 4 * rr][nb] = rb[rr];
    __syncthreads();

    const int NKT = K / 16;
    for (int kt = 0; kt < NKT; ++kt) {
        const int buf = kt & 1;
        if (kt + 1 < NKT) {
            int k0 = (kt + 1) * 16;
            ra[0] = ldA(k0, 0); ra[1] = ldA(k0, 1);
#pragma unroll
            for (int rr = 0; rr < 4; ++rr) rb[rr] = ldB(k0, rr);
        }
#pragma unroll
        for (int qq = 0; qq < 16; ++qq) {
            float2 a2 = *(const float2*)&As[buf][qq][ty * 2];
            float4 b4 = *(const float4*)&Bs[buf][qq][tx * 4];
            acc[0][0] += a2.x * b4.x; acc[0][1] += a2.x * b4.y;
            acc[0][2] += a2.x * b4.z; acc[0][3] += a2.x * b4.w;
            acc[1][0] += a2.y * b4.x; acc[1][1] += a2.y * b4.y;
            acc[1][2] += a2.y * b4.z; acc[1][3] += a2.y * b4.w;
        }
        if (kt + 1 < NKT) {
            const int nbuf = buf ^ 1;
            As[nbuf][sq][sm] = ra[0]; As[nbuf][sq][sm + 16] = ra[1];
#pragma unroll
            for (int rr = 0; rr < 4; ++rr) Bs[nbuf][kb + 4 * rr][nb] = rb[rr];
            __syncthreads();
        }
    }
#pragma unroll
    for (int i = 0; i < 2; ++i) {
        int m = m0 + ty * 2 + i;
        float* cp = &C[(size_t)m * N + n0 + tx * 4];
        float4 v = make_float4(acc[i][0], acc[i][1], acc[i][2], acc[i][3]);
        if (ACC) {
            float4 o = *(const float4*)cp;
            v.x += o.x; v.y += o.y; v.z += o.z; v.w += o.w;
        }
        *(float4*)cp = v;
    }
}

// logits -> softmax over 4 classes
__global__ __launch_bounds__(256)
void final_kernel(const float* __restrict__ pre,
                  const float* __restrict__ fc_w,
                  const float* __restrict__ fc_b,
                  float* __restrict__ out)
{
    int b = blockIdx.x;
    float acc[NC] = {0.f, 0.f, 0.f, 0.f};
    for (int k = threadIdx.x; k < H; k += 256) {
        float hs = tanh_fast(pre[(size_t)b * H + k]);
#pragma unroll
        for (int cc = 0; cc < NC; ++cc) acc[cc] += hs * fc_w[cc * H + k];
    }
    __shared__ float red[NC][256];
#pragma unroll
    for (int cc = 0; cc < NC; ++cc) red[cc][threadIdx.x] = acc[cc];
    __syncthreads();
    for (int off = 128; off > 0; off >>= 1) {
        if (threadIdx.x < off)
#pragma unroll
            for (int cc = 0; cc < NC; ++cc)
                red[cc][threadIdx.x] += red[cc][threadIdx.x + off];
        __syncthreads();
    }
    if (threadIdx.x == 0) {
        float l[NC], mx = -1e30f;
#pragma unroll
        for (int cc = 0; cc < NC; ++cc) { l[cc] = red[cc][0] + fc_b[cc]; mx = fmaxf(mx, l[cc]); }
        float sum = 0.f;
#pragma unroll
        for (int cc = 0; cc < NC; ++cc) { l[cc] = __expf(l[cc] - mx); sum += l[cc]; }
#pragma unroll
        for (int cc = 0; cc < NC; ++cc) out[b * NC + cc] = l[cc] / sum;
    }
}

extern "C" void kernel_launch(void* const* d_in, const int* in_sizes, int n_in,
                              void* d_out, int out_size, void* d_ws, size_t ws_size,
                              hipStream_t stream)
{
    const int*   prem   = (const int*)d_in[0];
    const int*   hyp    = (const int*)d_in[1];
    const float* emb    = (const float*)d_in[2];
    const float* w_ih_p = (const float*)d_in[3];
    const float* w_hh_p = (const float*)d_in[4];
    const float* b_ih_p = (const float*)d_in[5];
    const float* b_hh_p = (const float*)d_in[6];
    const float* w_ih_h = (const float*)d_in[7];
    const float* w_hh_h = (const float*)d_in[8];
    const float* b_ih_h = (const float*)d_in[9];
    const float* b_hh_h = (const float*)d_in[10];
    const float* wy     = (const float*)d_in[11];
    const float* wh     = (const float*)d_in[12];
    const float* wr     = (const float*)d_in[13];
    const float* wv     = (const float*)d_in[14];
    const float* wt     = (const float*)d_in[15];
    const float* wp     = (const float*)d_in[16];
    const float* wx     = (const float*)d_in[17];
    const float* fc_w   = (const float*)d_in[18];
    const float* fc_b   = (const float*)d_in[19];
    float* out = (float*)d_out;
    (void)in_sizes; (void)n_in; (void)out_size; (void)ws_size;

    char* wsc = (char*)d_ws;
    size_t off = 0;
    auto alloc = [&](size_t bytes) -> void* {
        void* p = wsc + off;
        off += (bytes + 255) & ~(size_t)255;
        return p;
    };
    constexpr size_t WSZ = (size_t)G4H * KCAT * 2;       // 11,010,048 B
    constexpr size_t SLAB = BHE * 4;                     // 512 KB (u32 h slab)

    // region A: LSTM weight packs (44 MB); reused as rseq during attn
    char* regionA = (char*)alloc(4 * WSZ);
    u16* Wp_hi = (u16*)regionA;
    u16* Wp_lo = (u16*)(regionA + WSZ);
    u16* Wq_hi = (u16*)(regionA + 2 * WSZ);
    u16* Wq_lo = (u16*)(regionA + 3 * WSZ);
    u32* rseq  = (u32*)regionA;                          // (SH+1)*SLAB = 32.5 MB

    u16* wyT_hi = (u16*)alloc((size_t)H * H * 2);
    u16* wyT_lo = (u16*)alloc((size_t)H * H * 2);
    u16* whT_hi = (u16*)alloc((size_t)H * H * 2);
    u16* whT_lo = (u16*)alloc((size_t)H * H * 2);
    u16* WrtH   = (u16*)alloc((size_t)2 * H * H * 2);
    u16* WrtL   = (u16*)alloc((size_t)2 * H * H * 2);

    u16* Y_hi   = (u16*)alloc((size_t)B * SP * H * 2);   // 32 MB
    u16* Y_lo   = (u16*)alloc((size_t)B * SP * H * 2);

    // region E (64 MB): hseqP (lstm_p) -> OH (lstm_h) -> first (gemm#2..attn)
    char* regionE = (char*)alloc((size_t)SP * SLAB);     // 128 * 512 KB
    u32* hseqP  = (u32*)regionE;
    u16* OH_hi  = (u16*)regionE;
    u16* OH_lo  = (u16*)(regionE + (size_t)SH * B * H * 2);
    u16* firstH = (u16*)regionE;
    u16* firstL = (u16*)(regionE + (size_t)B * SP * H * 2);

    // region F (32 MB): hseqH (lstm_h) -> hsec (gemm#1..attn)
    char* regionF = (char*)alloc((size_t)SH * SLAB);     // 64 * 512 KB
    u32* hseqH = (u32*)regionF;
    u16* hsecH = (u16*)regionF;
    u16* hsecL = (u16*)(regionF + (size_t)SH * B * H * 2);

    u32* h0zero = (u32*)alloc(SLAB);
    float* cbuf = (float*)alloc(SLAB);     // c, hm, cm contiguous
    float* hm   = (float*)alloc(SLAB);
    float* cm   = (float*)alloc(SLAB);
    float* r    = (float*)alloc(SLAB);
    float* srt  = (float*)alloc((size_t)B * 2048 * 4);
    float* sglob= (float*)alloc((size_t)B * SP * 4);
    float* pre  = (float*)alloc(SLAB);
    int*   bars = (int*)alloc(3 * 256 * sizeof(int));
    int* barP = bars; int* barH = bars + 256; int* barA = bars + 512;

    // -------- one-time splits --------
    dim3 gW((KCAT + 255) / 256, G4H);
    wcat_split_kernel<<<gW, 256, 0, stream>>>(w_ih_p, w_hh_p, Wp_hi, Wp_lo);
    wcat_split_kernel<<<gW, 256, 0, stream>>>(w_ih_h, w_hh_h, Wq_hi, Wq_lo);
    tsplit_kernel<<<dim3(H / 256, H), 256, 0, stream>>>(wy, wyT_hi, wyT_lo);
    tsplit_kernel<<<dim3(H / 256, H), 256, 0, stream>>>(wh, whT_hi, whT_lo);
    wrt_split_kernel<<<dim3(H / 256, 2 * H), 256, 0, stream>>>(wr, wt, WrtH, WrtL);

    hipMemsetAsync(h0zero, 0, SLAB, stream);
    hipMemsetAsync(cbuf, 0, 3 * SLAB, stream);    // c, hm, cm
    hipMemsetAsync(bars, 0, 3 * 256 * sizeof(int), stream);

    // -------- premise LSTM (persistent, h history in regionE) --------
    lstm_scan<1><<<NB_L, 256, 0, stream>>>(
        prem, SP, emb, Wp_hi, Wp_lo, b_ih_p, b_hh_p,
        h0zero, hseqP, cbuf, hm, cm, Y_hi, Y_lo, barP);

    // -------- hypothesis LSTM: h=0, c = cm; writes OH over dead hseqP --------
    hipMemsetAsync(hm, 0, SLAB, stream);
    lstm_scan<0><<<NB_L, 256, 0, stream>>>(
        hyp, SH, emb, Wq_hi, Wq_lo, b_ih_h, b_hh_h,
        h0zero, hseqH, cm, hm, (float*)nullptr, OH_hi, OH_lo, barH);
    // hm = out_h_last

    // -------- hoisted GEMMs: #1 (OH->hsec over dead hseqH) MUST precede
    //          #2 (Y->first overwrites OH) --------
    gemm_mfma_kernel<true><<<dim3(H / 64, (SH * B) / 64), 256, 0, stream>>>(
        OH_hi, OH_lo, whT_hi, whT_lo, nullptr, hsecH, hsecL, SH * B, H, H);
    gemm_mfma_kernel<true><<<dim3(H / 64, (B * SP) / 64), 256, 0, stream>>>(
        Y_hi, Y_lo, wyT_hi, wyT_lo, nullptr, firstH, firstL, B * SP, H, H);

    // -------- attention scan (persistent, 256 blocks) --------
    hipMemsetAsync(rseq, 0, SLAB, stream);        // rseq[0] = 0 (over dead Wp)
    hipMemsetAsync(r, 0, SLAB, stream);
    attn_scan<<<NB_A, 256, 0, stream>>>(
        firstH, firstL, hsecH, hsecL, WrtH, WrtL, Y_hi, Y_lo, wv, prem, hyp,
        srt, sglob, rseq, r, barA);

    // -------- final projection + softmax --------
    skinny_kernel<false><<<dim3(16, 4), 256, 0, stream>>>(r,  wp, pre, nullptr, nullptr, H, H, 16);
    skinny_kernel<true ><<<dim3(16, 4), 256, 0, stream>>>(hm, wx, pre, nullptr, nullptr, H, H, 16);
    final_kernel<<<B, 256, 0, stream>>>(pre, fc_w, fc_b, out);
}

// Round 7
// 10312.246 us; speedup vs baseline: 2.6022x; 1.0731x over previous
//
#include <hip/hip_runtime.h>

// SNLI attention-LSTM, MI355X. Round 7: group-local barriers + 512-block attn
// + packed hi|lo u32 streams.
//  - Dataflow analysis: LSTM block (bx,by) needs h only from the 64 blocks
//    with the same by -> 4 independent 64-block barrier groups. Attention:
//    srt rows [16g,16g+16) produced/consumed by those b's 64 blocks (16b x 4
//    subs); sglob[b] by b's 4 blocks -> 64-group + 4-sub barriers, no grid
//    barrier anywhere.
//  - attn: 512 blocks (2/CU resident: 66KB LDS each), 4 subs/b; phase C
//    p-loop split across thread halves (64-deep chains + LDS combine).
//  - Y/OH/first/hsec stored as packed u32 (bf16hi<<16|bf16lo): same bytes,
//    half the load instructions. gemm unpacks A, writes packed C.

using u16 = unsigned short;
using u32 = unsigned int;
using u64 = unsigned long long;
typedef short bf16x8 __attribute__((ext_vector_type(8)));
typedef float f32x4 __attribute__((ext_vector_type(4)));

constexpr int B  = 128;
constexpr int SP = 128;
constexpr int SH = 64;
constexpr int H  = 1024;
constexpr int E  = 300;
constexpr int NC = 4;
constexpr int G4H  = 4 * H;          // 4096
constexpr int EPAD = 320;            // E padded to multiple of 32
constexpr int KCAT = EPAD + H;       // 1344
constexpr int NB_L = 256;            // lstm blocks (4 groups of 64)
constexpr int NB_A = 512;            // attn blocks (8 groups of 64; 4 per b)
constexpr size_t BHE = (size_t)B * H;

__device__ __forceinline__ float sigf(float x) { return 1.0f / (1.0f + __expf(-x)); }
__device__ __forceinline__ float tanh_fast(float x) {
    float e = __expf(2.0f * x);
    return 1.0f - 2.0f / (e + 1.0f);
}
__device__ __forceinline__ u16 f2bf(float x) {           // round-to-nearest-even
    union { float f; unsigned u; } v; v.f = x;
    unsigned r = v.u + 0x7fffu + ((v.u >> 16) & 1u);
    return (u16)(r >> 16);
}
__device__ __forceinline__ float bf2f(u16 h) {
    union { unsigned u; float f; } v; v.u = ((unsigned)h) << 16;
    return v.f;
}
__device__ __forceinline__ float uaf(u32 u) { return __uint_as_float(u); }
__device__ __forceinline__ float unpk(u32 v) {           // hi + lo
    return uaf(v & 0xffff0000u) + uaf(v << 16);
}
__device__ __forceinline__ f32x4 mfma16(bf16x8 a, bf16x8 b, f32x4 c) {
    return __builtin_amdgcn_mfma_f32_16x16x32_bf16(a, b, c, 0, 0, 0);
}
__device__ __forceinline__ u32 packhl(float v) {
    u16 hi = f2bf(v);
    u16 lo = f2bf(v - bf2f(hi));
    return ((u32)hi << 16) | lo;
}

// ---- coherence-point (agent scope, relaxed) accessors ----
__device__ __forceinline__ float aLdF(const float* p) {
    return __hip_atomic_load(p, __ATOMIC_RELAXED, __HIP_MEMORY_SCOPE_AGENT);
}
__device__ __forceinline__ void aStF(float* p, float v) {
    __hip_atomic_store(p, v, __ATOMIC_RELAXED, __HIP_MEMORY_SCOPE_AGENT);
}
__device__ __forceinline__ void aSt32(u32* p, u32 v) {
    __hip_atomic_store(p, v, __ATOMIC_RELAXED, __HIP_MEMORY_SCOPE_AGENT);
}
__device__ __forceinline__ void aSt64(u64* p, u64 v) {
    __hip_atomic_store(p, v, __ATOMIC_RELAXED, __HIP_MEMORY_SCOPE_AGENT);
}

// ---- group-local flag barrier ----
__device__ __forceinline__ void grp_arrive(int* flags, int epoch) {
    asm volatile("s_waitcnt vmcnt(0)" ::: "memory");   // this wave's stores done
    __syncthreads();                                   // all waves done
    if (threadIdx.x == 0)
        __hip_atomic_store(&flags[blockIdx.x], epoch,
                           __ATOMIC_RELAXED, __HIP_MEMORY_SCOPE_AGENT);
}
__device__ __forceinline__ void grp_wait(int* flags, int base, int n, int epoch) {
    for (;;) {
        int v = (threadIdx.x < n)
            ? __hip_atomic_load(&flags[base + (int)threadIdx.x],
                                __ATOMIC_RELAXED, __HIP_MEMORY_SCOPE_AGENT)
            : epoch;
        if (__syncthreads_and(v >= epoch)) break;
        __builtin_amdgcn_s_sleep(4);
    }
    asm volatile("" ::: "memory");
    __builtin_amdgcn_sched_barrier(0);
}

// ---------------------------------------------------------------------------
// Prep kernels
// ---------------------------------------------------------------------------
__global__ __launch_bounds__(256)
void wcat_split_kernel(const float* __restrict__ w_ih, const float* __restrict__ w_hh,
                       u16* __restrict__ dh, u16* __restrict__ dl)
{
    int col = blockIdx.x * 256 + threadIdx.x;
    int n = blockIdx.y;
    if (col >= KCAT) return;
    float v = 0.f;
    if (col < E)          v = w_ih[(size_t)n * E + col];
    else if (col >= EPAD) v = w_hh[(size_t)n * H + (col - EPAD)];
    u16 hi = f2bf(v);
    dh[(size_t)n * KCAT + col] = hi;
    dl[(size_t)n * KCAT + col] = f2bf(v - bf2f(hi));
}

__global__ __launch_bounds__(256)
void tsplit_kernel(const float* __restrict__ src, u16* __restrict__ dh, u16* __restrict__ dl)
{
    int k = blockIdx.x * 256 + threadIdx.x;
    int n = blockIdx.y;
    float v = src[(size_t)k * H + n];
    u16 hi = f2bf(v);
    dh[(size_t)n * H + k] = hi;
    dl[(size_t)n * H + k] = f2bf(v - bf2f(hi));
}

__global__ __launch_bounds__(256)
void wrt_split_kernel(const float* __restrict__ wr, const float* __restrict__ wt,
                      u16* __restrict__ dh, u16* __restrict__ dl)
{
    int k = blockIdx.x * 256 + threadIdx.x;    // 0..H-1
    int n = blockIdx.y;                        // 0..2047
    float v = (n < H) ? wr[(size_t)k * H + n] : wt[(size_t)k * H + (n - H)];
    u16 hi = f2bf(v);
    dh[(size_t)n * H + k] = hi;
    dl[(size_t)n * H + k] = f2bf(v - bf2f(hi));
}

// ---------------------------------------------------------------------------
// Persistent LSTM scan. 256 blocks x 256 thr. Barrier groups = 64 blocks
// sharing by (h-slab locality). h history hseq[t] packed u32: coherent
// writes, cached reads (fresh address per t).
// ---------------------------------------------------------------------------
template<int PREMISE>
__global__ __launch_bounds__(256, 1)
void lstm_scan(const int* __restrict__ toks, int S,
               const float* __restrict__ emb,
               const u16* __restrict__ Wh, const u16* __restrict__ Wl,
               const float* __restrict__ b_ih, const float* __restrict__ b_hh,
               const u32* __restrict__ h0,    // zeros
               u32* __restrict__ hseq,        // [S][B][H] packed history
               float* __restrict__ c, float* __restrict__ hmask,
               float* __restrict__ cmask,
               u32* __restrict__ seq_pk,      // packed outputs (Y or outh)
               int* __restrict__ flags)
{
    const int tid  = threadIdx.x;
    const int lane = tid & 63;
    const int g    = tid >> 6;           // gate = wave
    const int l15  = lane & 15;
    const int lk8  = (lane >> 4) * 8;
    const int bx   = blockIdx.x & 63;
    const int by   = blockIdx.x >> 6;    // 0..3 (barrier group)
    const int k0   = bx * 16;
    const int m0   = by * 32;
    const int gbase = by * 64;

    // resident weights: rows n = g*H + k0 + l15, cols ks*32 + lk8
    bf16x8 wh_r[42], wl_r[42];
    {
        const u16* ph = Wh + (size_t)(g * H + k0 + l15) * KCAT + lk8;
        const u16* pl = Wl + (size_t)(g * H + k0 + l15) * KCAT + lk8;
#pragma unroll
        for (int ks = 0; ks < 42; ++ks) {
            wh_r[ks] = *(const bf16x8*)(ph + ks * 32);
            wl_r[ks] = *(const bf16x8*)(pl + ks * 32);
        }
    }
    const int ke = k0 + (tid & 15);
    const float bs0 = b_ih[0 * H + ke] + b_hh[0 * H + ke];
    const float bs1 = b_ih[1 * H + ke] + b_hh[1 * H + ke];
    const float bs2 = b_ih[2 * H + ke] + b_hh[2 * H + ke];
    const float bs3 = b_ih[3 * H + ke] + b_hh[3 * H + ke];

    __shared__ u16 hiL[32][1032];        // 66 KB
    __shared__ u16 loL[32][1032];        // 66 KB
    __shared__ float gt[4][32][17];      // 8.7 KB

    for (int t = 0; t < S; ++t) {
        const u32* hin = (t == 0) ? h0 : (hseq + (size_t)(t - 1) * BHE);
        u32*      hout = hseq + (size_t)t * BHE;

        const float* ea[2];
#pragma unroll
        for (int mt = 0; mt < 2; ++mt) {
            int row = m0 + mt * 16 + l15;
            int tok = toks[row * S + t];
            ea[mt] = emb + (size_t)tok * E + lk8;
        }

        f32x4 acc[2] = {{0.f,0.f,0.f,0.f},{0.f,0.f,0.f,0.f}};

        // ---- emb segment (independent of previous h) ----
#pragma unroll
        for (int ks = 0; ks < 9; ++ks) {
#pragma unroll
            for (int mt = 0; mt < 2; ++mt) {
                float4 f0 = *(const float4*)(ea[mt] + ks * 32);
                float4 f1 = *(const float4*)(ea[mt] + ks * 32 + 4);
                float v[8] = {f0.x, f0.y, f0.z, f0.w, f1.x, f1.y, f1.z, f1.w};
                bf16x8 a_hi, a_lo;
#pragma unroll
                for (int j = 0; j < 8; ++j) {
                    u16 hi = f2bf(v[j]);
                    a_hi[j] = (short)hi;
                    a_lo[j] = (short)f2bf(v[j] - bf2f(hi));
                }
                acc[mt] = mfma16(a_hi, wh_r[ks], acc[mt]);
                acc[mt] = mfma16(a_lo, wh_r[ks], acc[mt]);
                acc[mt] = mfma16(a_hi, wl_r[ks], acc[mt]);
            }
        }
        {   // ks = 9: cols 288 + lk8 + j, guard k < E (weight pad cols are 0)
#pragma unroll
            for (int mt = 0; mt < 2; ++mt) {
                float v[8];
#pragma unroll
                for (int j = 0; j < 8; ++j) {
                    int k = 288 + lk8 + j;
                    v[j] = (k < E) ? ea[mt][k - lk8] : 0.f;
                }
                bf16x8 a_hi, a_lo;
#pragma unroll
                for (int j = 0; j < 8; ++j) {
                    u16 hi = f2bf(v[j]);
                    a_hi[j] = (short)hi;
                    a_lo[j] = (short)f2bf(v[j] - bf2f(hi));
                }
                acc[mt] = mfma16(a_hi, wh_r[9], acc[mt]);
                acc[mt] = mfma16(a_lo, wh_r[9], acc[mt]);
                acc[mt] = mfma16(a_hi, wl_r[9], acc[mt]);
            }
        }

        // ---- wait for previous step's h (group-local: 64 blocks of same by) ----
        if (t > 0) grp_wait(flags, gbase, 64, t);

        // ---- cooperative stage: hin rows m0..m0+31 -> LDS (CACHED loads) ----
        {
            const u64* hsrc = (const u64*)(hin + (size_t)m0 * H);
#pragma unroll 16
            for (int j = 0; j < 64; ++j) {
                int i = j * 256 + tid;
                u64 v = hsrc[i];
                u32 p0 = (u32)v, p1 = (u32)(v >> 32);
                int row = i >> 9, cp = (i & 511) * 2;
                *(u32*)&hiL[row][cp] = (p0 >> 16) | (p1 & 0xffff0000u);
                *(u32*)&loL[row][cp] = (p0 & 0xffffu) | (p1 << 16);
            }
        }
        __syncthreads();

        // ---- h segment from LDS ----
#pragma unroll
        for (int ks = 0; ks < 32; ++ks) {
#pragma unroll
            for (int mt = 0; mt < 2; ++mt) {
                bf16x8 a_hi = *(const bf16x8*)&hiL[mt * 16 + l15][ks * 32 + lk8];
                bf16x8 a_lo = *(const bf16x8*)&loL[mt * 16 + l15][ks * 32 + lk8];
                acc[mt] = mfma16(a_hi, wh_r[10 + ks], acc[mt]);
                acc[mt] = mfma16(a_lo, wh_r[10 + ks], acc[mt]);
                acc[mt] = mfma16(a_hi, wl_r[10 + ks], acc[mt]);
            }
        }
        __syncthreads();                 // hiL/loL reads done (reused next t)

        // ---- gate exchange via LDS ----
#pragma unroll
        for (int mt = 0; mt < 2; ++mt)
#pragma unroll
            for (int j = 0; j < 4; ++j)
                gt[g][mt * 16 + (lane >> 4) * 4 + j][l15] = acc[mt][j];
        __syncthreads();

        // ---- cell epilogue ----
#pragma unroll
        for (int i = 0; i < 2; ++i) {
            int ml = (tid >> 4) + i * 16;        // 0..31
            int m  = m0 + ml;
            size_t idx = (size_t)m * H + ke;
            float gi = gt[0][ml][tid & 15] + bs0;
            float gf = gt[1][ml][tid & 15] + bs1;
            float gg = gt[2][ml][tid & 15] + bs2;
            float go = gt[3][ml][tid & 15] + bs3;
            float c2 = sigf(gf) * c[idx] + sigf(gi) * tanh_fast(gg);
            float h2 = sigf(go) * tanh_fast(c2);
            c[idx] = c2;                          // block-private
            aSt32(&hout[idx], packhl(h2));        // coherent (fresh slot)
            float mk = (toks[m * S + t] != 0) ? 1.f : 0.f;
            float hmv = mk * h2 + (1.f - mk) * hmask[idx];
            hmask[idx] = hmv;                     // block-private
            u16 mh = f2bf(hmv);
            u16 mlv = f2bf(hmv - bf2f(mh));
            u32 pk = ((u32)mh << 16) | mlv;
            if (PREMISE) {
                float cmv = mk * c2 + (1.f - mk) * cmask[idx];
                cmask[idx] = cmv;
                seq_pk[((size_t)m * SP + t) * H + ke] = pk;   // Y [B][SP][H]
            } else {
                seq_pk[((size_t)t * B + m) * H + ke] = pk;    // outh [SH][B][H]
            }
        }
        if (t + 1 < S) grp_arrive(flags, t + 1);
    }
}

// ---------------------------------------------------------------------------
// Persistent attention scan. 512 blocks x 256 thr; b = blockIdx>>2,
// sub = blockIdx&3. Barrier groups: 64 blocks (16 b's) via gflags; 4-block
// sub-barrier per b via sflags. first/hsec/Y packed u32; r history rseq[t].
// ---------------------------------------------------------------------------
__global__ __launch_bounds__(256, 1)
void attn_scan(const u32* __restrict__ first_pk,  // [B*SP][H] packed
               const u32* __restrict__ hsec_pk,   // [SH*B][H] packed
               const u16* __restrict__ Wrth, const u16* __restrict__ Wrtl, // [2048][1024]
               const u32* __restrict__ Ypk,       // [B*SP][H] packed
               const float* __restrict__ wv,
               const int* __restrict__ ptoks, const int* __restrict__ htoks,
               float* __restrict__ srt,           // [B][2048] coherent
               float* __restrict__ sglob,         // [B][SP] coherent scores
               u32* __restrict__ rseq,            // [SH+1][B][H] packed history
               float* __restrict__ r,             // [B][H] fp32 (sub-owned cols)
               int* __restrict__ gflags, int* __restrict__ sflags)
{
    const int tid  = threadIdx.x;
    const int lane = tid & 63;
    const int w    = tid >> 6;
    const int l15  = lane & 15;
    const int lk8  = (lane >> 4) * 8;
    const int b    = blockIdx.x >> 2;
    const int sub  = blockIdx.x & 3;
    const int grp  = blockIdx.x >> 6;          // group of 64 blocks (16 b's)
    const int gbase = grp * 64;
    const int ig   = blockIdx.x & 63;          // index within group
    const int sbase = b * 4;

    __shared__ u16 rs_hi[16][1032];      // 33 KB
    __shared__ u16 rs_lo[16][1032];      // 33 KB
    __shared__ float al[SP];             // 512 B
    __shared__ float red[SP];            // 512 B
    __shared__ float ps[128][2];         // 1 KB

    float wv_e[16];
#pragma unroll
    for (int e = 0; e < 16; ++e) wv_e[e] = wv[lane + e * 64];

    const int pm0 = grp * 16;                  // group's 16 batch rows
    const int n0  = (ig * 2 + w) * 16;         // wave tile col (w<2 active)
    const ptrdiff_t dB = Wrtl - Wrth;

    for (int t = 0; t < SH; ++t) {
        // ---- stage rseq[t] rows pm0..pm0+15 -> LDS (cached, fresh addr) ----
        {
            const u64* rsrc = (const u64*)(rseq + (size_t)t * BHE + (size_t)pm0 * H);
#pragma unroll 16
            for (int j = 0; j < 32; ++j) {
                int i = j * 256 + tid;
                u64 v = rsrc[i];
                u32 p0 = (u32)v, p1 = (u32)(v >> 32);
                int row = i >> 9, cp = (i & 511) * 2;
                *(u32*)&rs_hi[row][cp] = (p0 >> 16) | (p1 & 0xffff0000u);
                *(u32*)&rs_lo[row][cp] = (p0 & 0xffffu) | (p1 << 16);
            }
        }
        __syncthreads();

        // ---- phase A: srt[pm0..+15][n0..+15] (waves 0,1 only) ----
        if (w < 2) {
            const u16* bp0 = Wrth + (size_t)(n0 + l15) * H + lk8;
            f32x4 a0 = {0.f,0.f,0.f,0.f};
#pragma unroll 4
            for (int ks = 0; ks < 32; ++ks) {
                bf16x8 ahi = *(const bf16x8*)&rs_hi[l15][ks * 32 + lk8];
                bf16x8 alo = *(const bf16x8*)&rs_lo[l15][ks * 32 + lk8];
                bf16x8 b0h = *(const bf16x8*)(bp0 + ks * 32);
                bf16x8 b0l = *(const bf16x8*)(bp0 + dB + ks * 32);
                a0 = mfma16(ahi, b0h, a0);
                a0 = mfma16(alo, b0h, a0);
                a0 = mfma16(ahi, b0l, a0);
            }
#pragma unroll
            for (int j = 0; j < 4; ++j) {
                int mrow = pm0 + (lane >> 4) * 4 + j;
                aStF(&srt[(size_t)mrow * 2048 + n0 + l15], a0[j]);
            }
        }
        grp_arrive(gflags, 2 * t + 1);
        grp_wait(gflags, gbase, 64, 2 * t + 1);

        // ---- phase B: scores for own p-quarter (32 p's) ----
        {
            float hsum[16];
            const u32* hpk = hsec_pk + ((size_t)t * B + b) * H;
            const float* sb = srt + (size_t)b * 2048;
#pragma unroll
            for (int e = 0; e < 16; ++e) {
                int hh = lane + e * 64;
                hsum[e] = unpk(hpk[hh]) + aLdF(&sb[hh]);
            }
            for (int pp = 0; pp < 8; ++pp) {
                int p = sub * 32 + w * 8 + pp;
                const u32* fpk = first_pk + ((size_t)b * SP + p) * H;
                float acc = 0.f;
#pragma unroll
                for (int e = 0; e < 16; ++e)
                    acc += tanh_fast(unpk(fpk[lane + e * 64]) + hsum[e]) * wv_e[e];
#pragma unroll
                for (int off = 32; off; off >>= 1) acc += __shfl_xor(acc, off);
                if (lane == 0)
                    aStF(&sglob[b * SP + p],
                         acc + ((ptoks[b * SP + p] != 0) ? 0.f : -1000.f));
            }
        }
        grp_arrive(sflags, t + 1);
        grp_wait(sflags, sbase, 4, t + 1);

        // ---- phase C: softmax + r update over own 256 cols ----
        {
            if (tid < SP) { float v = aLdF(&sglob[b * SP + tid]); al[tid] = v; red[tid] = v; }
            __syncthreads();
            for (int off = 64; off; off >>= 1) {
                if (tid < off) red[tid] = fmaxf(red[tid], red[tid + off]);
                __syncthreads();
            }
            float mx = red[0];
            __syncthreads();
            if (tid < SP) { float e = __expf(al[tid] - mx); al[tid] = e; red[tid] = e; }
            __syncthreads();
            for (int off = 64; off; off >>= 1) {
                if (tid < off) red[tid] += red[tid + off];
                __syncthreads();
            }
            float inv = 1.f / red[0];
            __syncthreads();
            if (tid < SP) al[tid] *= inv;
            __syncthreads();

            const int half = tid >> 7;           // 0: p 0..63, 1: p 64..127
            const int tl   = tid & 127;
            const int c0   = sub * 256 + tl * 2;
            const u32* yp = Ypk + (size_t)b * SP * H + c0;
            float s0 = 0.f, s1 = 0.f;
#pragma unroll 4
            for (int pp = 0; pp < 64; ++pp) {
                int p = half * 64 + pp;
                float a = al[p];
                u64 v = *(const u64*)(yp + (size_t)p * H);
                s0 += a * unpk((u32)v);
                s1 += a * unpk((u32)(v >> 32));
            }
            if (half) { ps[tl][0] = s0; ps[tl][1] = s1; }
            __syncthreads();
            if (!half) {
                s0 += ps[tl][0]; s1 += ps[tl][1];
                float mk = (htoks[b * SH + t] != 0) ? 1.f : 0.f;
                float rn0 = s0 + tanh_fast(aLdF(&srt[(size_t)b * 2048 + H + c0]));
                float rn1 = s1 + tanh_fast(aLdF(&srt[(size_t)b * 2048 + H + c0 + 1]));
                float ro0 = r[(size_t)b * H + c0];
                float ro1 = r[(size_t)b * H + c0 + 1];
                float rv0 = mk * rn0 + (1.f - mk) * ro0;
                float rv1 = mk * rn1 + (1.f - mk) * ro1;
                r[(size_t)b * H + c0]     = rv0;
                r[(size_t)b * H + c0 + 1] = rv1;
                aSt64((u64*)(rseq + (size_t)(t + 1) * BHE + (size_t)b * H + c0),
                      ((u64)packhl(rv1) << 32) | packhl(rv0));
            }
        }
        if (t + 1 < SH) {
            grp_arrive(gflags, 2 * t + 2);
            grp_wait(gflags, gbase, 64, 2 * t + 2);
        }
    }
}

// ---------------------------------------------------------------------------
// Split-bf16 MFMA GEMM, packed A/C: C_pk = A_pk[M,K] @ B^T, B [N][K] hi/lo.
// ---------------------------------------------------------------------------
__global__ __launch_bounds__(256)
void gemm_pk_kernel(const u32* __restrict__ Apk,
                    const u16* __restrict__ Bh, const u16* __restrict__ Bl,
                    u32* __restrict__ Cpk, int M, int N, int K)
{
    const int tid  = threadIdx.x;
    const int lane = tid & 63;
    const int wave = tid >> 6;
    const int l15  = lane & 15;
    const int lk8  = (lane >> 4) * 8;
    const int m0   = blockIdx.y * 64 + wave * 16;
    const int n0   = blockIdx.x * 64;

    const u32* ap = Apk + (size_t)(m0 + l15) * K + lk8;
    const u16* bhp[4]; const u16* blp[4];
#pragma unroll
    for (int nt = 0; nt < 4; ++nt) {
        size_t o = (size_t)(n0 + nt * 16 + l15) * K + lk8;
        bhp[nt] = Bh + o; blp[nt] = Bl + o;
    }
    f32x4 acc[4] = {{0.f,0.f,0.f,0.f},{0.f,0.f,0.f,0.f},
                    {0.f,0.f,0.f,0.f},{0.f,0.f,0.f,0.f}};
    const int nks = K >> 5;
#pragma unroll 2
    for (int ks = 0; ks < nks; ++ks) {
        uint4 v0 = *(const uint4*)(ap + ks * 32);
        uint4 v1 = *(const uint4*)(ap + ks * 32 + 4);
        u32 vv[8] = {v0.x, v0.y, v0.z, v0.w, v1.x, v1.y, v1.z, v1.w};
        bf16x8 a_hi, a_lo;
#pragma unroll
        for (int j = 0; j < 8; ++j) {
            a_hi[j] = (short)(vv[j] >> 16);
            a_lo[j] = (short)(vv[j] & 0xffffu);
        }
#pragma unroll
        for (int nt = 0; nt < 4; ++nt) {
            bf16x8 b_hi = *(const bf16x8*)(bhp[nt] + ks * 32);
            bf16x8 b_lo = *(const bf16x8*)(blp[nt] + ks * 32);
            acc[nt] = mfma16(a_hi, b_hi, acc[nt]);
            acc[nt] = mfma16(a_lo, b_hi, acc[nt]);
            acc[nt] = mfma16(a_hi, b_lo, acc[nt]);
        }
    }
#pragma unroll
    for (int nt = 0; nt < 4; ++nt)
#pragma unroll
        for (int j = 0; j < 4; ++j) {
            int m = m0 + (lane >> 4) * 4 + j;
            Cpk[(size_t)m * N + n0 + nt * 16 + l15] = packhl(acc[nt][j]);
        }
}

// ---------------------------------------------------------------------------
// Skinny fp32 GEMM (M=128): tile 32x64, BK=16, 256 thr, dbuf (verified).
// ---------------------------------------------------------------------------
template<bool ACC>
__global__ __launch_bounds__(256)
void skinny_kernel(const float* __restrict__ A,
                   const float* __restrict__ B1, float* __restrict__ C1,
                   const float* __restrict__ B2, float* __restrict__ C2,
                   int K, int N, int ntiles)
{
    const int tid = threadIdx.x;
    const int tx = tid & 15, ty = tid >> 4;
    const int bx = blockIdx.x;
    const float* Bw = (bx < ntiles) ? B1 : B2;
    float* C       = (bx < ntiles) ? C1 : C2;
    const int n0 = ((bx < ntiles) ? bx : bx - ntiles) * 64;
    const int m0 = blockIdx.y * 32;

    __shared__ float As[2][16][34];
    __shared__ float Bs[2][16][68];
    const int sq = tid & 15, sm = tid >> 4;
    const int nb = tid & 63, kb = tid >> 6;

    float ra[2], rb[4];
    auto ldA = [&](int k0, int rr) -> float {
        return A[(size_t)(m0 + sm + 16 * rr) * K + k0 + sq];
    };
    auto ldB = [&](int k0, int rr) -> float {
        return Bw[(size_t)(k0 + kb + 4 * rr) * N + n0 + nb];
    };

    float acc[2][4] = {};
    ra[0] = ldA(0, 0); ra[1] = ldA(0, 1);
#pragma unroll
    for (int rr = 0; rr < 4; ++rr) rb[rr] = ldB(0, rr);
    As[0][sq][sm] = ra[0]; As[0][sq][sm + 16] = ra[1];
#pragma unroll
    for (int rr = 0; rr < 4; ++rr) Bs[0][kb + 4 * rr][nb] = rb[rr];
    __syncthreads();

    const int NKT = K / 16;
    for (int kt = 0; kt < NKT; ++kt) {
        const int buf = kt & 1;
        if (kt + 1 < NKT) {
            int k0 = (kt + 1) * 16;
            ra[0] = ldA(k0, 0); ra[1] = ldA(k0, 1);
#pragma unroll
            for (int rr = 0; rr < 4; ++rr) rb[rr] = ldB(k0, rr);
        }
#pragma unroll
        for (int qq = 0; qq < 16; ++qq) {
            float2 a2 = *(const float2*)&As[buf][qq][ty * 2];
            float4 b4 = *(const float4*)&Bs[buf][qq][tx * 4];
            acc[0][0] += a2.x * b4.x; acc[0][1] += a2.x * b4.y;
            acc[0][2] += a2.x * b4.z; acc[0][3] += a2.x * b4.w;
            acc[1][0] += a2.y * b4.x; acc[1][1] += a2.y * b4.y;
            acc[1][2] += a2.y * b4.z; acc[1][3] += a2.y * b4.w;
        }
        if (kt + 1 < NKT) {
            const int nbuf = buf ^ 1;
            As[nbuf][sq][sm] = ra[0]; As[nbuf][sq][sm + 16] = ra[1];
#pragma unroll
            for (int rr = 0; rr < 4; ++rr) Bs[nbuf][kb + 4 * rr][nb] = rb[rr];
            __syncthreads();
        }
    }
#pragma unroll
    for (int i = 0; i < 2; ++i) {
        int m = m0 + ty * 2 + i;
        float* cp = &C[(size_t)m * N + n0 + tx * 4];
        float4 v = make_float4(acc[i][0], acc[i][1], acc[i][2], acc[i][3]);
        if (ACC) {
            float4 o = *(const float4*)cp;
            v.x += o.x; v.y += o.y; v.z += o.z; v.w += o.w;
        }
        *(float4*)cp = v;
    }
}

// logits -> softmax over 4 classes
__global__ __launch_bounds__(256)
void final_kernel(const float* __restrict__ pre,
                  const float* __restrict__ fc_w,
                  const float* __restrict__ fc_b,
                  float* __restrict__ out)
{
    int b = blockIdx.x;
    float acc[NC] = {0.f, 0.f, 0.f, 0.f};
    for (int k = threadIdx.x; k < H; k += 256) {
        float hs = tanh_fast(pre[(size_t)b * H + k]);
#pragma unroll
        for (int cc = 0; cc < NC; ++cc) acc[cc] += hs * fc_w[cc * H + k];
    }
    __shared__ float red[NC][256];
#pragma unroll
    for (int cc = 0; cc < NC; ++cc) red[cc][threadIdx.x] = acc[cc];
    __syncthreads();
    for (int off = 128; off > 0; off >>= 1) {
        if (threadIdx.x < off)
#pragma unroll
            for (int cc = 0; cc < NC; ++cc)
                red[cc][threadIdx.x] += red[cc][threadIdx.x + off];
        __syncthreads();
    }
    if (threadIdx.x == 0) {
        float l[NC], mx = -1e30f;
#pragma unroll
        for (int cc = 0; cc < NC; ++cc) { l[cc] = red[cc][0] + fc_b[cc]; mx = fmaxf(mx, l[cc]); }
        float sum = 0.f;
#pragma unroll
        for (int cc = 0; cc < NC; ++cc) { l[cc] = __expf(l[cc] - mx); sum += l[cc]; }
#pragma unroll
        for (int cc = 0; cc < NC; ++cc) out[b * NC + cc] = l[cc] / sum;
    }
}

extern "C" void kernel_launch(void* const* d_in, const int* in_sizes, int n_in,
                              void* d_out, int out_size, void* d_ws, size_t ws_size,
                              hipStream_t stream)
{
    const int*   prem   = (const int*)d_in[0];
    const int*   hyp    = (const int*)d_in[1];
    const float* emb    = (const float*)d_in[2];
    const float* w_ih_p = (const float*)d_in[3];
    const float* w_hh_p = (const float*)d_in[4];
    const float* b_ih_p = (const float*)d_in[5];
    const float* b_hh_p = (const float*)d_in[6];
    const float* w_ih_h = (const float*)d_in[7];
    const float* w_hh_h = (const float*)d_in[8];
    const float* b_ih_h = (const float*)d_in[9];
    const float* b_hh_h = (const float*)d_in[10];
    const float* wy     = (const float*)d_in[11];
    const float* wh     = (const float*)d_in[12];
    const float* wr     = (const float*)d_in[13];
    const float* wv     = (const float*)d_in[14];
    const float* wt     = (const float*)d_in[15];
    const float* wp     = (const float*)d_in[16];
    const float* wx     = (const float*)d_in[17];
    const float* fc_w   = (const float*)d_in[18];
    const float* fc_b   = (const float*)d_in[19];
    float* out = (float*)d_out;
    (void)in_sizes; (void)n_in; (void)out_size; (void)ws_size;

    char* wsc = (char*)d_ws;
    size_t off = 0;
    auto alloc = [&](size_t bytes) -> void* {
        void* p = wsc + off;
        off += (bytes + 255) & ~(size_t)255;
        return p;
    };
    constexpr size_t WSZ = (size_t)G4H * KCAT * 2;       // 11,010,048 B
    constexpr size_t SLAB = BHE * 4;                     // 512 KB

    // region A: LSTM weight packs (44 MB); reused as rseq during attn
    char* regionA = (char*)alloc(4 * WSZ);
    u16* Wp_hi = (u16*)regionA;
    u16* Wp_lo = (u16*)(regionA + WSZ);
    u16* Wq_hi = (u16*)(regionA + 2 * WSZ);
    u16* Wq_lo = (u16*)(regionA + 3 * WSZ);
    u32* rseq  = (u32*)regionA;                          // (SH+1)*SLAB = 32.5 MB

    u16* wyT_hi = (u16*)alloc((size_t)H * H * 2);
    u16* wyT_lo = (u16*)alloc((size_t)H * H * 2);
    u16* whT_hi = (u16*)alloc((size_t)H * H * 2);
    u16* whT_lo = (u16*)alloc((size_t)H * H * 2);
    u16* WrtH   = (u16*)alloc((size_t)2 * H * H * 2);
    u16* WrtL   = (u16*)alloc((size_t)2 * H * H * 2);

    u32* Ypk = (u32*)alloc((size_t)B * SP * H * 4);      // 64 MB packed

    // region E (64 MB): hseqP (lstm_p) -> OHpk (lstm_h) -> first_pk
    char* regionE = (char*)alloc((size_t)SP * SLAB);
    u32* hseqP    = (u32*)regionE;
    u32* OHpk     = (u32*)regionE;                       // 32 MB
    u32* first_pk = (u32*)regionE;                       // 64 MB

    // region F (32 MB): hseqH (lstm_h) -> hsec_pk
    char* regionF = (char*)alloc((size_t)SH * SLAB);
    u32* hseqH   = (u32*)regionF;
    u32* hsec_pk = (u32*)regionF;

    u32* h0zero = (u32*)alloc(SLAB);
    float* cbuf = (float*)alloc(SLAB);     // c, hm, cm contiguous
    float* hm   = (float*)alloc(SLAB);
    float* cm   = (float*)alloc(SLAB);
    float* r    = (float*)alloc(SLAB);
    float* srt  = (float*)alloc((size_t)B * 2048 * 4);
    float* sglob= (float*)alloc((size_t)B * SP * 4);
    float* pre  = (float*)alloc(SLAB);
    int* barP   = (int*)alloc(256 * sizeof(int));
    int* barH   = (int*)alloc(256 * sizeof(int));
    int* gflA   = (int*)alloc(512 * sizeof(int));
    int* sflA   = (int*)alloc(512 * sizeof(int));

    // -------- one-time splits --------
    dim3 gW((KCAT + 255) / 256, G4H);
    wcat_split_kernel<<<gW, 256, 0, stream>>>(w_ih_p, w_hh_p, Wp_hi, Wp_lo);
    wcat_split_kernel<<<gW, 256, 0, stream>>>(w_ih_h, w_hh_h, Wq_hi, Wq_lo);
    tsplit_kernel<<<dim3(H / 256, H), 256, 0, stream>>>(wy, wyT_hi, wyT_lo);
    tsplit_kernel<<<dim3(H / 256, H), 256, 0, stream>>>(wh, whT_hi, whT_lo);
    wrt_split_kernel<<<dim3(H / 256, 2 * H), 256, 0, stream>>>(wr, wt, WrtH, WrtL);

    hipMemsetAsync(h0zero, 0, SLAB, stream);
    hipMemsetAsync(cbuf, 0, 3 * SLAB, stream);    // c, hm, cm
    hipMemsetAsync(barP, 0, 256 * sizeof(int), stream);
    hipMemsetAsync(barH, 0, 256 * sizeof(int), stream);
    hipMemsetAsync(gflA, 0, 512 * sizeof(int), stream);
    hipMemsetAsync(sflA, 0, 512 * sizeof(int), stream);

    // -------- premise LSTM (persistent; history in regionE) --------
    lstm_scan<1><<<NB_L, 256, 0, stream>>>(
        prem, SP, emb, Wp_hi, Wp_lo, b_ih_p, b_hh_p,
        h0zero, hseqP, cbuf, hm, cm, Ypk, barP);

    // -------- hypothesis LSTM: h=0, c = cm; OHpk over dead hseqP --------
    hipMemsetAsync(hm, 0, SLAB, stream);
    lstm_scan<0><<<NB_L, 256, 0, stream>>>(
        hyp, SH, emb, Wq_hi, Wq_lo, b_ih_h, b_hh_h,
        h0zero, hseqH, cm, hm, (float*)nullptr, OHpk, barH);
    // hm = out_h_last

    // -------- hoisted GEMMs: #1 (OH->hsec over dead hseqH) BEFORE
    //          #2 (Y->first, overwrites OH region) --------
    gemm_pk_kernel<<<dim3(H / 64, (SH * B) / 64), 256, 0, stream>>>(
        OHpk, whT_hi, whT_lo, hsec_pk, SH * B, H, H);
    gemm_pk_kernel<<<dim3(H / 64, (B * SP) / 64), 256, 0, stream>>>(
        Ypk, wyT_hi, wyT_lo, first_pk, B * SP, H, H);

    // -------- attention scan (persistent, 512 blocks) --------
    hipMemsetAsync(rseq, 0, SLAB, stream);        // rseq[0] = 0 (dead Wp)
    hipMemsetAsync(r, 0, SLAB, stream);
    attn_scan<<<NB_A, 256, 0, stream>>>(
        first_pk, hsec_pk, WrtH, WrtL, Ypk, wv, prem, hyp,
        srt, sglob, rseq, r, gflA, sflA);

    // -------- final projection + softmax --------
    skinny_kernel<false><<<dim3(16, 4), 256, 0, stream>>>(r,  wp, pre, nullptr, nullptr, H, H, 16);
    skinny_kernel<true ><<<dim3(16, 4), 256, 0, stream>>>(hm, wx, pre, nullptr, nullptr, H, H, 16);
    final_kernel<<<B, 256, 0, stream>>>(pre, fc_w, fc_b, out);
}